// Round 6
// baseline (506.507 us; speedup 1.0000x reference)
//
#include <hip/hip_runtime.h>
#include <stdint.h>

#define N_NODES 50000
#define N_EDGES 800000
#define IN_CH 128
#define HID 256
#define N_GRAPHS 64
#define N_CLASSES 10

#define SCAN_BLOCKS ((N_NODES + 255) / 256)   // 196
#define GEMM_MT ((N_NODES + 127) / 128)       // 391 row tiles
#define GEMM_WG (GEMM_MT * 2)                 // 782 blocks (2 col tiles)

typedef unsigned short u16;
typedef __attribute__((ext_vector_type(8))) short short8;
typedef __attribute__((ext_vector_type(4))) float f32x4;

__device__ __forceinline__ float bf2f(uint32_t u) {
    union { uint32_t i; float f; } v; v.i = u << 16; return v.f;
}
__device__ __forceinline__ uint32_t f2bf(float f) {
    union { float f; uint32_t i; } v; v.f = f;
    return (v.i + 0x7FFFu + ((v.i >> 16) & 1u)) >> 16;   // RNE
}

// ===========================================================================
// CSR build
// ===========================================================================
__global__ void hist_kernel(const int* __restrict__ dst, int* __restrict__ deg)
{
    int e = blockIdx.x * blockDim.x + threadIdx.x;
    if (e < N_EDGES) atomicAdd(&deg[dst[e]], 1);
}

__global__ void __launch_bounds__(256) scan_p1(const int* __restrict__ deg, int* __restrict__ bsum)
{
    __shared__ int buf[256];
    int i = blockIdx.x * 256 + threadIdx.x;
    int v = (i < N_NODES) ? deg[i] : 0;
    buf[threadIdx.x] = v;
    __syncthreads();
    #pragma unroll
    for (int off = 128; off > 0; off >>= 1) {
        if (threadIdx.x < off) buf[threadIdx.x] += buf[threadIdx.x + off];
        __syncthreads();
    }
    if (threadIdx.x == 0) bsum[blockIdx.x] = buf[0];
}

__global__ void __launch_bounds__(256) scan_p2(const int* __restrict__ bsum,
                                               int* __restrict__ boff,
                                               int* __restrict__ row_start)
{
    __shared__ int buf[256];
    int t = threadIdx.x;
    int v = (t < SCAN_BLOCKS) ? bsum[t] : 0;
    buf[t] = v;
    __syncthreads();
    #pragma unroll
    for (int off = 1; off < 256; off <<= 1) {
        int a = (t >= off) ? buf[t - off] : 0;
        __syncthreads();
        buf[t] += a;
        __syncthreads();
    }
    if (t < SCAN_BLOCKS) boff[t] = buf[t] - v;
    if (t == 255) row_start[N_NODES] = buf[255];
}

__global__ void __launch_bounds__(256) scan_p3(const int* __restrict__ deg,
                                               const int* __restrict__ boff,
                                               int* __restrict__ row_start,
                                               int* __restrict__ cursor)
{
    __shared__ int buf[256];
    int t = threadIdx.x;
    int i = blockIdx.x * 256 + t;
    int v = (i < N_NODES) ? deg[i] : 0;
    buf[t] = v;
    __syncthreads();
    #pragma unroll
    for (int off = 1; off < 256; off <<= 1) {
        int a = (t >= off) ? buf[t - off] : 0;
        __syncthreads();
        buf[t] += a;
        __syncthreads();
    }
    if (i < N_NODES) {
        int rs = boff[blockIdx.x] + buf[t] - v;
        row_start[i] = rs;
        cursor[i] = rs;
    }
}

__global__ void fill_kernel(const int* __restrict__ src, const int* __restrict__ dst,
                            int* __restrict__ cursor, int* __restrict__ esrc)
{
    int e = blockIdx.x * blockDim.x + threadIdx.x;
    if (e < N_EDGES) {
        int pos = atomicAdd(&cursor[dst[e]], 1);
        esrc[pos] = src[e];
    }
}

// ===========================================================================
// fp32 -> bf16 conversions
// ===========================================================================
__global__ void cvt_x_kernel(const float* __restrict__ x, u16* __restrict__ xb)
{
    int id = blockIdx.x * blockDim.x + threadIdx.x;
    if (id >= N_NODES * (IN_CH / 8)) return;
    const float4 a = *reinterpret_cast<const float4*>(x + (size_t)id * 8);
    const float4 b = *reinterpret_cast<const float4*>(x + (size_t)id * 8 + 4);
    uint4 o;
    o.x = f2bf(a.x) | (f2bf(a.y) << 16);
    o.y = f2bf(a.z) | (f2bf(a.w) << 16);
    o.z = f2bf(b.x) | (f2bf(b.y) << 16);
    o.w = f2bf(b.z) | (f2bf(b.w) << 16);
    *reinterpret_cast<uint4*>(xb + (size_t)id * 8) = o;
}

__global__ void twt_kernel(const float* W0, const float* W1, const float* W2, const float* W3,
                           u16* o0, u16* o1, u16* o2, u16* o3, int K, int nmat)
{
    int id = blockIdx.x * blockDim.x + threadIdx.x;
    int per = K * HID;
    int m = id / per;
    if (m >= nmat) return;
    int r = id % per;
    int k = r / HID, n = r % HID;
    const float* W = (m == 0) ? W0 : (m == 1) ? W1 : (m == 2) ? W2 : W3;
    u16* O = (m == 0) ? o0 : (m == 1) ? o1 : (m == 2) ? o2 : o3;
    O[(size_t)n * K + k] = (u16)f2bf(W[r]);
}

// ===========================================================================
// agg[i,:] = sum_{j in in(i)} feat[j,:]  — XCD-chunked for L2 residency.
// chunk = blockIdx & 7 -> with round-robin block->XCD dispatch, XCD c only
// touches feat columns [c*D/8, (c+1)*D/8): working set D=256 -> 3.2 MB < 4 MB L2.
// LPN lanes (16B each) per node per chunk; fp32 accumulate; bf16 out.
// ===========================================================================
template<int D>
__global__ void __launch_bounds__(256)
gather_bf(const u16* __restrict__ feat, const int* __restrict__ row_start,
          const int* __restrict__ esrc, u16* __restrict__ agg)
{
    constexpr int CPC = D / 8;         // cols per chunk (32 or 16)
    constexpr int LPN = CPC / 8;       // lanes per node (4 or 2)
    constexpr int NPB = 256 / LPN;     // nodes per block (64 or 128)
    const int chunk = blockIdx.x & 7;
    const int tile  = blockIdx.x >> 3;
    const int node  = tile * NPB + threadIdx.x / LPN;
    const int lane  = threadIdx.x % LPN;
    if (node >= N_NODES) return;
    const int s = row_start[node], e = row_start[node + 1];
    float acc[8] = {0.f, 0.f, 0.f, 0.f, 0.f, 0.f, 0.f, 0.f};
    const u16* fp = feat + chunk * CPC + lane * 8;

    auto add = [&](uint4 v) {
        acc[0] += bf2f(v.x & 0xFFFF); acc[1] += bf2f(v.x >> 16);
        acc[2] += bf2f(v.y & 0xFFFF); acc[3] += bf2f(v.y >> 16);
        acc[4] += bf2f(v.z & 0xFFFF); acc[5] += bf2f(v.z >> 16);
        acc[6] += bf2f(v.w & 0xFFFF); acc[7] += bf2f(v.w >> 16);
    };

    int j = s;
    for (; j + 3 < e; j += 4) {
        int s0 = esrc[j], s1 = esrc[j + 1], s2 = esrc[j + 2], s3 = esrc[j + 3];
        uint4 v0 = *reinterpret_cast<const uint4*>(fp + (size_t)s0 * D);
        uint4 v1 = *reinterpret_cast<const uint4*>(fp + (size_t)s1 * D);
        uint4 v2 = *reinterpret_cast<const uint4*>(fp + (size_t)s2 * D);
        uint4 v3 = *reinterpret_cast<const uint4*>(fp + (size_t)s3 * D);
        add(v0); add(v1); add(v2); add(v3);
    }
    for (; j < e; ++j) {
        uint4 v0 = *reinterpret_cast<const uint4*>(fp + (size_t)esrc[j] * D);
        add(v0);
    }
    uint4 o;
    o.x = f2bf(acc[0]) | (f2bf(acc[1]) << 16);
    o.y = f2bf(acc[2]) | (f2bf(acc[3]) << 16);
    o.z = f2bf(acc[4]) | (f2bf(acc[5]) << 16);
    o.w = f2bf(acc[6]) | (f2bf(acc[7]) << 16);
    *reinterpret_cast<uint4*>(agg + (size_t)node * D + chunk * CPC + lane * 8) = o;
}

// ===========================================================================
// C[m,n] = act( A1@W1 + A2@W2 + bias )   — bf16 MFMA, fp32 acc, bf16 out
// ===========================================================================
template<int RELU>
__global__ void __launch_bounds__(256)
mfma_gemm(const u16* __restrict__ A1, const u16* __restrict__ A2,
          const u16* __restrict__ B1t, const u16* __restrict__ B2t,
          const float* __restrict__ bias,
          u16* __restrict__ C,
          int M, int K)
{
    __shared__ __align__(16) u16 As[128][40];
    __shared__ __align__(16) u16 Bs[128][40];

    const int orig = blockIdx.x;
    const int q = GEMM_WG / 8, r = GEMM_WG % 8;
    const int xcd = orig % 8;
    const int wg = (xcd < r ? xcd * (q + 1) : r * (q + 1) + (xcd - r) * q) + orig / 8;

    const int tid = threadIdx.x;
    const int bm = (wg >> 1) * 128;
    const int bn = (wg & 1) * 128;
    const int w  = tid >> 6;
    const int wm = (w >> 1) * 64;
    const int wn = (w & 1) * 64;
    const int l  = tid & 63;
    const int lr = l & 15;
    const int kb = (l >> 4) * 8;

    f32x4 acc[4][4];
    #pragma unroll
    for (int i = 0; i < 4; ++i)
        #pragma unroll
        for (int j = 0; j < 4; ++j)
            acc[i][j] = (f32x4){0.f, 0.f, 0.f, 0.f};

    const int row_s = tid >> 2;
    const int c8    = (tid & 3) * 8;

    for (int mat = 0; mat < 2; ++mat) {
        const u16* __restrict__ Ag = mat ? A2 : A1;
        const u16* __restrict__ Bg = mat ? B2t : B1t;
        for (int k0 = 0; k0 < K; k0 += 32) {
            #pragma unroll
            for (int it = 0; it < 2; ++it) {
                int row = row_s + it * 64;
                uint4 va = make_uint4(0u, 0u, 0u, 0u);
                int gr = bm + row;
                if (gr < M)
                    va = *reinterpret_cast<const uint4*>(Ag + (size_t)gr * K + k0 + c8);
                *reinterpret_cast<uint4*>(&As[row][c8]) = va;
                uint4 vb = *reinterpret_cast<const uint4*>(Bg + (size_t)(bn + row) * K + k0 + c8);
                *reinterpret_cast<uint4*>(&Bs[row][c8]) = vb;
            }
            __syncthreads();
            short8 af[4], bfr[4];
            #pragma unroll
            for (int f = 0; f < 4; ++f) {
                af[f]  = *reinterpret_cast<const short8*>(&As[wm + f * 16 + lr][kb]);
                bfr[f] = *reinterpret_cast<const short8*>(&Bs[wn + f * 16 + lr][kb]);
            }
            #pragma unroll
            for (int fm = 0; fm < 4; ++fm)
                #pragma unroll
                for (int fn = 0; fn < 4; ++fn)
                    acc[fm][fn] = __builtin_amdgcn_mfma_f32_16x16x32_bf16(
                        af[fm], bfr[fn], acc[fm][fn], 0, 0, 0);
            __syncthreads();
        }
    }

    const int r4 = (l >> 4) * 4;
    #pragma unroll
    for (int fm = 0; fm < 4; ++fm) {
        #pragma unroll
        for (int rr = 0; rr < 4; ++rr) {
            int row = bm + wm + fm * 16 + r4 + rr;
            if (row >= M) continue;
            #pragma unroll
            for (int fn = 0; fn < 4; ++fn) {
                int col = bn + wn + fn * 16 + lr;
                float v = acc[fm][fn][rr] + bias[col];
                if (RELU) v = fmaxf(v, 0.f);
                C[(size_t)row * HID + col] = (u16)f2bf(v);
            }
        }
    }
}

// ===========================================================================
// Pooling (batch sorted): inline binary search, two-stage mean
// ===========================================================================
__device__ __forceinline__ int lower_bound_g(const int* __restrict__ batch, int g)
{
    int lo = 0, hi = N_NODES;
    while (lo < hi) {
        int mid = (lo + hi) >> 1;
        if (batch[mid] < g) lo = mid + 1; else hi = mid;
    }
    return lo;
}

__global__ void pool1_kernel(const u16* __restrict__ h, const int* __restrict__ batch,
                             float* __restrict__ partial)
{
    int g = blockIdx.x >> 3;
    int c = blockIdx.x & 7;
    int t = threadIdx.x;      // 256
    int s = lower_bound_g(batch, g);
    int e = lower_bound_g(batch, g + 1);
    int cnt = e - s;
    int a = s + (int)(((long long)cnt * c) >> 3);
    int b = s + (int)(((long long)cnt * (c + 1)) >> 3);
    float acc = 0.f;
    for (int i = a; i < b; ++i)
        acc += bf2f(h[(size_t)i * HID + t]);
    partial[(size_t)blockIdx.x * HID + t] = acc;
}

__global__ void pool2_kernel(const float* __restrict__ partial, const int* __restrict__ batch,
                             float* __restrict__ pooled)
{
    int g = blockIdx.x;
    int t = threadIdx.x;
    float acc = 0.f;
    #pragma unroll
    for (int c = 0; c < 8; ++c)
        acc += partial[(size_t)(g * 8 + c) * HID + t];
    float cnt = fmaxf((float)(lower_bound_g(batch, g + 1) - lower_bound_g(batch, g)), 1.f);
    pooled[g * HID + t] = acc / cnt;
}

__global__ void final_kernel(const float* __restrict__ pooled,
                             const float* __restrict__ W_lin,
                             const float* __restrict__ b_lin,
                             float* __restrict__ out)
{
    __shared__ float v[HID];
    int g = blockIdx.x;
    int t = threadIdx.x;
    v[t] = pooled[g * HID + t];
    __syncthreads();
    if (t < N_CLASSES) {
        float s = b_lin[t];
        for (int k = 0; k < HID; ++k)
            s += v[k] * W_lin[k * N_CLASSES + t];
        out[g * N_CLASSES + t] = s;
    }
}

// ===========================================================================
extern "C" void kernel_launch(void* const* d_in, const int* in_sizes, int n_in,
                              void* d_out, int out_size, void* d_ws, size_t ws_size,
                              hipStream_t stream)
{
    const float* x     = (const float*)d_in[0];
    const int*   ei    = (const int*)d_in[1];
    const int*   batch = (const int*)d_in[2];
    const float* W1r = (const float*)d_in[3];
    const float* W1n = (const float*)d_in[4];
    const float* b1  = (const float*)d_in[5];
    const float* W2r = (const float*)d_in[6];
    const float* W2n = (const float*)d_in[7];
    const float* b2  = (const float*)d_in[8];
    const float* W3r = (const float*)d_in[9];
    const float* W3n = (const float*)d_in[10];
    const float* b3  = (const float*)d_in[11];
    const float* Wl  = (const float*)d_in[12];
    const float* bl  = (const float*)d_in[13];
    float* out = (float*)d_out;

    const int* src = ei;
    const int* dst = ei + N_EDGES;

    char* base = (char*)d_ws;
    size_t off = 0;
    auto alloc = [&](size_t bytes) { char* p = base + off; off += (bytes + 255) & ~(size_t)255; return p; };
    u16* x_bf = (u16*)alloc((size_t)N_NODES * IN_CH * 2);
    u16* hA   = (u16*)alloc((size_t)N_NODES * HID * 2);
    u16* hB   = (u16*)alloc((size_t)N_NODES * HID * 2);
    u16* agg  = (u16*)alloc((size_t)N_NODES * HID * 2);
    u16* wt1r = (u16*)alloc((size_t)HID * IN_CH * 2);
    u16* wt1n = (u16*)alloc((size_t)HID * IN_CH * 2);
    u16* wt2r = (u16*)alloc((size_t)HID * HID * 2);
    u16* wt2n = (u16*)alloc((size_t)HID * HID * 2);
    u16* wt3r = (u16*)alloc((size_t)HID * HID * 2);
    u16* wt3n = (u16*)alloc((size_t)HID * HID * 2);
    float* partial = (float*)alloc((size_t)N_GRAPHS * 8 * HID * 4);
    float* pooled  = (float*)alloc((size_t)N_GRAPHS * HID * 4);
    int* deg       = (int*)alloc((size_t)N_NODES * 4);
    int* row_start = (int*)alloc((size_t)(N_NODES + 1) * 4);
    int* cursor    = (int*)alloc((size_t)N_NODES * 4);
    int* esrc      = (int*)alloc((size_t)N_EDGES * 4);
    int* bsum      = (int*)alloc((size_t)SCAN_BLOCKS * 4);
    int* boff      = (int*)alloc((size_t)SCAN_BLOCKS * 4);

    const int EB = (N_EDGES + 255) / 256;

    // ---- CSR build ----
    hipMemsetAsync(deg, 0, N_NODES * sizeof(int), stream);
    hist_kernel<<<EB, 256, 0, stream>>>(dst, deg);
    scan_p1<<<SCAN_BLOCKS, 256, 0, stream>>>(deg, bsum);
    scan_p2<<<1, 256, 0, stream>>>(bsum, boff, row_start);
    scan_p3<<<SCAN_BLOCKS, 256, 0, stream>>>(deg, boff, row_start, cursor);
    fill_kernel<<<EB, 256, 0, stream>>>(src, dst, cursor, esrc);

    // ---- conversions ----
    cvt_x_kernel<<<(N_NODES * (IN_CH / 8) + 255) / 256, 256, 0, stream>>>(x, x_bf);
    twt_kernel<<<(2 * IN_CH * HID + 255) / 256, 256, 0, stream>>>(
        W1r, W1n, nullptr, nullptr, wt1r, wt1n, nullptr, nullptr, IN_CH, 2);
    twt_kernel<<<(4 * HID * HID + 255) / 256, 256, 0, stream>>>(
        W2r, W2n, W3r, W3n, wt2r, wt2n, wt3r, wt3n, HID, 4);

    // gather grids: node-tiles x 8 chunks
    const int GT128 = ((N_NODES + 127) / 128) * 8;   // D=128: 128 nodes/block
    const int GT256 = ((N_NODES + 63) / 64) * 8;     // D=256: 64 nodes/block

    // ---- layer 1 (K=128, relu) ----
    gather_bf<IN_CH><<<GT128, 256, 0, stream>>>(x_bf, row_start, esrc, agg);
    mfma_gemm<1><<<GEMM_WG, 256, 0, stream>>>(x_bf, agg, wt1r, wt1n, b1, hA, N_NODES, IN_CH);

    // ---- layer 2 (K=256, relu) ----
    gather_bf<HID><<<GT256, 256, 0, stream>>>(hA, row_start, esrc, agg);
    mfma_gemm<1><<<GEMM_WG, 256, 0, stream>>>(hA, agg, wt2r, wt2n, b2, hB, N_NODES, HID);

    // ---- layer 3 (K=256, no relu) ----
    gather_bf<HID><<<GT256, 256, 0, stream>>>(hB, row_start, esrc, agg);
    mfma_gemm<0><<<GEMM_WG, 256, 0, stream>>>(hB, agg, wt3r, wt3n, b3, hA, N_NODES, HID);

    // ---- pool + classifier ----
    pool1_kernel<<<N_GRAPHS * 8, HID, 0, stream>>>(hA, batch, partial);
    pool2_kernel<<<N_GRAPHS, HID, 0, stream>>>(partial, batch, pooled);
    final_kernel<<<N_GRAPHS, HID, 0, stream>>>(pooled, Wl, bl, out);
}

// Round 7
// 411.815 us; speedup vs baseline: 1.2299x; 1.2299x over previous
//
#include <hip/hip_runtime.h>
#include <stdint.h>

#define N_NODES 50000
#define N_EDGES 800000
#define IN_CH 128
#define HID 256
#define N_GRAPHS 64
#define N_CLASSES 10

#define SCAN_BLOCKS ((N_NODES + 255) / 256)   // 196
#define GEMM_MT ((N_NODES + 127) / 128)       // 391 row tiles
#define GEMM_WG (GEMM_MT * 2)                 // 782 blocks (2 col tiles)

typedef unsigned short u16;
typedef __attribute__((ext_vector_type(8))) short short8;
typedef __attribute__((ext_vector_type(4))) float f32x4;

__device__ __forceinline__ float bf2f(uint32_t u) {
    union { uint32_t i; float f; } v; v.i = u << 16; return v.f;
}
__device__ __forceinline__ uint32_t f2bf(float f) {
    union { float f; uint32_t i; } v; v.f = f;
    return (v.i + 0x7FFFu + ((v.i >> 16) & 1u)) >> 16;   // RNE
}

// ===========================================================================
// CSR build
// ===========================================================================
__global__ void hist_kernel(const int* __restrict__ dst, int* __restrict__ deg)
{
    int e = blockIdx.x * blockDim.x + threadIdx.x;
    if (e < N_EDGES) atomicAdd(&deg[dst[e]], 1);
}

__global__ void __launch_bounds__(256) scan_p1(const int* __restrict__ deg, int* __restrict__ bsum)
{
    __shared__ int buf[256];
    int i = blockIdx.x * 256 + threadIdx.x;
    int v = (i < N_NODES) ? deg[i] : 0;
    buf[threadIdx.x] = v;
    __syncthreads();
    #pragma unroll
    for (int off = 128; off > 0; off >>= 1) {
        if (threadIdx.x < off) buf[threadIdx.x] += buf[threadIdx.x + off];
        __syncthreads();
    }
    if (threadIdx.x == 0) bsum[blockIdx.x] = buf[0];
}

__global__ void __launch_bounds__(256) scan_p2(const int* __restrict__ bsum,
                                               int* __restrict__ boff,
                                               int* __restrict__ row_start)
{
    __shared__ int buf[256];
    int t = threadIdx.x;
    int v = (t < SCAN_BLOCKS) ? bsum[t] : 0;
    buf[t] = v;
    __syncthreads();
    #pragma unroll
    for (int off = 1; off < 256; off <<= 1) {
        int a = (t >= off) ? buf[t - off] : 0;
        __syncthreads();
        buf[t] += a;
        __syncthreads();
    }
    if (t < SCAN_BLOCKS) boff[t] = buf[t] - v;
    if (t == 255) row_start[N_NODES] = buf[255];
}

__global__ void __launch_bounds__(256) scan_p3(const int* __restrict__ deg,
                                               const int* __restrict__ boff,
                                               int* __restrict__ row_start,
                                               int* __restrict__ cursor)
{
    __shared__ int buf[256];
    int t = threadIdx.x;
    int i = blockIdx.x * 256 + t;
    int v = (i < N_NODES) ? deg[i] : 0;
    buf[t] = v;
    __syncthreads();
    #pragma unroll
    for (int off = 1; off < 256; off <<= 1) {
        int a = (t >= off) ? buf[t - off] : 0;
        __syncthreads();
        buf[t] += a;
        __syncthreads();
    }
    if (i < N_NODES) {
        int rs = boff[blockIdx.x] + buf[t] - v;
        row_start[i] = rs;
        cursor[i] = rs;
    }
}

// 4 sub-passes over disjoint dst ranges: concurrent writes target a ~800 KB
// region so 64 B write sectors fill before eviction (was 52 MB WRITE for
// 3.2 MB payload). Passes touch disjoint cursors -> no cross-pass ordering.
__global__ void fill_kernel(const int* __restrict__ src, const int* __restrict__ dst,
                            int* __restrict__ cursor, int* __restrict__ esrc)
{
    int e = blockIdx.x * blockDim.x + threadIdx.x;
    if (e >= N_EDGES) return;
    int d = dst[e];
    int s = src[e];
    const int RANGE = (N_NODES + 3) / 4;   // 12500
    #pragma unroll
    for (int p = 0; p < 4; ++p) {
        if (d >= p * RANGE && d < (p + 1) * RANGE) {
            int pos = atomicAdd(&cursor[d], 1);
            esrc[pos] = s;
        }
    }
}

// ===========================================================================
// fp32 -> bf16 conversions
// ===========================================================================
__global__ void cvt_x_kernel(const float* __restrict__ x, u16* __restrict__ xb)
{
    int id = blockIdx.x * blockDim.x + threadIdx.x;
    if (id >= N_NODES * (IN_CH / 8)) return;
    const float4 a = *reinterpret_cast<const float4*>(x + (size_t)id * 8);
    const float4 b = *reinterpret_cast<const float4*>(x + (size_t)id * 8 + 4);
    uint4 o;
    o.x = f2bf(a.x) | (f2bf(a.y) << 16);
    o.y = f2bf(a.z) | (f2bf(a.w) << 16);
    o.z = f2bf(b.x) | (f2bf(b.y) << 16);
    o.w = f2bf(b.z) | (f2bf(b.w) << 16);
    *reinterpret_cast<uint4*>(xb + (size_t)id * 8) = o;
}

__global__ void twt_kernel(const float* W0, const float* W1, const float* W2, const float* W3,
                           u16* o0, u16* o1, u16* o2, u16* o3, int K, int nmat)
{
    int id = blockIdx.x * blockDim.x + threadIdx.x;
    int per = K * HID;
    int m = id / per;
    if (m >= nmat) return;
    int r = id % per;
    int k = r / HID, n = r % HID;
    const float* W = (m == 0) ? W0 : (m == 1) ? W1 : (m == 2) ? W2 : W3;
    u16* O = (m == 0) ? o0 : (m == 1) ? o1 : (m == 2) ? o2 : o3;
    O[(size_t)n * K + k] = (u16)f2bf(W[r]);
}

// ===========================================================================
// agg[i,:] = sum_{j in in(i)} feat[j,:]  — bf16, fp32 acc, 4-deep unroll
// (R5 form: full-row reads; ~3.4 TB/s L2-miss fabric rate is the floor)
// ===========================================================================
template<int D>
__global__ void __launch_bounds__(256)
gather_bf(const u16* __restrict__ feat, const int* __restrict__ row_start,
          const int* __restrict__ esrc, u16* __restrict__ agg)
{
    constexpr int GS = D / 8;
    constexpr int NPB = 256 / GS;
    int node = blockIdx.x * NPB + threadIdx.x / GS;
    int lane = threadIdx.x % GS;
    if (node >= N_NODES) return;
    const int s = row_start[node], e = row_start[node + 1];
    float acc[8] = {0.f, 0.f, 0.f, 0.f, 0.f, 0.f, 0.f, 0.f};
    const u16* fp = feat + lane * 8;

    auto add = [&](uint4 v) {
        acc[0] += bf2f(v.x & 0xFFFF); acc[1] += bf2f(v.x >> 16);
        acc[2] += bf2f(v.y & 0xFFFF); acc[3] += bf2f(v.y >> 16);
        acc[4] += bf2f(v.z & 0xFFFF); acc[5] += bf2f(v.z >> 16);
        acc[6] += bf2f(v.w & 0xFFFF); acc[7] += bf2f(v.w >> 16);
    };

    int j = s;
    for (; j + 3 < e; j += 4) {
        int s0 = esrc[j], s1 = esrc[j + 1], s2 = esrc[j + 2], s3 = esrc[j + 3];
        uint4 v0 = *reinterpret_cast<const uint4*>(fp + (size_t)s0 * D);
        uint4 v1 = *reinterpret_cast<const uint4*>(fp + (size_t)s1 * D);
        uint4 v2 = *reinterpret_cast<const uint4*>(fp + (size_t)s2 * D);
        uint4 v3 = *reinterpret_cast<const uint4*>(fp + (size_t)s3 * D);
        add(v0); add(v1); add(v2); add(v3);
    }
    for (; j < e; ++j) {
        uint4 v0 = *reinterpret_cast<const uint4*>(fp + (size_t)esrc[j] * D);
        add(v0);
    }
    uint4 o;
    o.x = f2bf(acc[0]) | (f2bf(acc[1]) << 16);
    o.y = f2bf(acc[2]) | (f2bf(acc[3]) << 16);
    o.z = f2bf(acc[4]) | (f2bf(acc[5]) << 16);
    o.w = f2bf(acc[6]) | (f2bf(acc[7]) << 16);
    *reinterpret_cast<uint4*>(agg + (size_t)node * D + lane * 8) = o;
}

// ===========================================================================
// C[m,n] = act( A1@W1 + A2@W2 + bias )   — bf16 MFMA, fp32 acc, bf16 out
// ===========================================================================
template<int RELU>
__global__ void __launch_bounds__(256)
mfma_gemm(const u16* __restrict__ A1, const u16* __restrict__ A2,
          const u16* __restrict__ B1t, const u16* __restrict__ B2t,
          const float* __restrict__ bias,
          u16* __restrict__ C,
          int M, int K)
{
    __shared__ __align__(16) u16 As[128][40];
    __shared__ __align__(16) u16 Bs[128][40];

    const int orig = blockIdx.x;
    const int q = GEMM_WG / 8, r = GEMM_WG % 8;
    const int xcd = orig % 8;
    const int wg = (xcd < r ? xcd * (q + 1) : r * (q + 1) + (xcd - r) * q) + orig / 8;

    const int tid = threadIdx.x;
    const int bm = (wg >> 1) * 128;
    const int bn = (wg & 1) * 128;
    const int w  = tid >> 6;
    const int wm = (w >> 1) * 64;
    const int wn = (w & 1) * 64;
    const int l  = tid & 63;
    const int lr = l & 15;
    const int kb = (l >> 4) * 8;

    f32x4 acc[4][4];
    #pragma unroll
    for (int i = 0; i < 4; ++i)
        #pragma unroll
        for (int j = 0; j < 4; ++j)
            acc[i][j] = (f32x4){0.f, 0.f, 0.f, 0.f};

    const int row_s = tid >> 2;
    const int c8    = (tid & 3) * 8;

    for (int mat = 0; mat < 2; ++mat) {
        const u16* __restrict__ Ag = mat ? A2 : A1;
        const u16* __restrict__ Bg = mat ? B2t : B1t;
        for (int k0 = 0; k0 < K; k0 += 32) {
            #pragma unroll
            for (int it = 0; it < 2; ++it) {
                int row = row_s + it * 64;
                uint4 va = make_uint4(0u, 0u, 0u, 0u);
                int gr = bm + row;
                if (gr < M)
                    va = *reinterpret_cast<const uint4*>(Ag + (size_t)gr * K + k0 + c8);
                *reinterpret_cast<uint4*>(&As[row][c8]) = va;
                uint4 vb = *reinterpret_cast<const uint4*>(Bg + (size_t)(bn + row) * K + k0 + c8);
                *reinterpret_cast<uint4*>(&Bs[row][c8]) = vb;
            }
            __syncthreads();
            short8 af[4], bfr[4];
            #pragma unroll
            for (int f = 0; f < 4; ++f) {
                af[f]  = *reinterpret_cast<const short8*>(&As[wm + f * 16 + lr][kb]);
                bfr[f] = *reinterpret_cast<const short8*>(&Bs[wn + f * 16 + lr][kb]);
            }
            #pragma unroll
            for (int fm = 0; fm < 4; ++fm)
                #pragma unroll
                for (int fn = 0; fn < 4; ++fn)
                    acc[fm][fn] = __builtin_amdgcn_mfma_f32_16x16x32_bf16(
                        af[fm], bfr[fn], acc[fm][fn], 0, 0, 0);
            __syncthreads();
        }
    }

    const int r4 = (l >> 4) * 4;
    #pragma unroll
    for (int fm = 0; fm < 4; ++fm) {
        #pragma unroll
        for (int rr = 0; rr < 4; ++rr) {
            int row = bm + wm + fm * 16 + r4 + rr;
            if (row >= M) continue;
            #pragma unroll
            for (int fn = 0; fn < 4; ++fn) {
                int col = bn + wn + fn * 16 + lr;
                float v = acc[fm][fn][rr] + bias[col];
                if (RELU) v = fmaxf(v, 0.f);
                C[(size_t)row * HID + col] = (u16)f2bf(v);
            }
        }
    }
}

// ===========================================================================
// Pooling (batch sorted): inline binary search, two-stage mean
// ===========================================================================
__device__ __forceinline__ int lower_bound_g(const int* __restrict__ batch, int g)
{
    int lo = 0, hi = N_NODES;
    while (lo < hi) {
        int mid = (lo + hi) >> 1;
        if (batch[mid] < g) lo = mid + 1; else hi = mid;
    }
    return lo;
}

__global__ void pool1_kernel(const u16* __restrict__ h, const int* __restrict__ batch,
                             float* __restrict__ partial)
{
    int g = blockIdx.x >> 3;
    int c = blockIdx.x & 7;
    int t = threadIdx.x;      // 256
    int s = lower_bound_g(batch, g);
    int e = lower_bound_g(batch, g + 1);
    int cnt = e - s;
    int a = s + (int)(((long long)cnt * c) >> 3);
    int b = s + (int)(((long long)cnt * (c + 1)) >> 3);
    float acc = 0.f;
    for (int i = a; i < b; ++i)
        acc += bf2f(h[(size_t)i * HID + t]);
    partial[(size_t)blockIdx.x * HID + t] = acc;
}

__global__ void pool2_kernel(const float* __restrict__ partial, const int* __restrict__ batch,
                             float* __restrict__ pooled)
{
    int g = blockIdx.x;
    int t = threadIdx.x;
    float acc = 0.f;
    #pragma unroll
    for (int c = 0; c < 8; ++c)
        acc += partial[(size_t)(g * 8 + c) * HID + t];
    float cnt = fmaxf((float)(lower_bound_g(batch, g + 1) - lower_bound_g(batch, g)), 1.f);
    pooled[g * HID + t] = acc / cnt;
}

__global__ void final_kernel(const float* __restrict__ pooled,
                             const float* __restrict__ W_lin,
                             const float* __restrict__ b_lin,
                             float* __restrict__ out)
{
    __shared__ float v[HID];
    int g = blockIdx.x;
    int t = threadIdx.x;
    v[t] = pooled[g * HID + t];
    __syncthreads();
    if (t < N_CLASSES) {
        float s = b_lin[t];
        for (int k = 0; k < HID; ++k)
            s += v[k] * W_lin[k * N_CLASSES + t];
        out[g * N_CLASSES + t] = s;
    }
}

// ===========================================================================
extern "C" void kernel_launch(void* const* d_in, const int* in_sizes, int n_in,
                              void* d_out, int out_size, void* d_ws, size_t ws_size,
                              hipStream_t stream)
{
    const float* x     = (const float*)d_in[0];
    const int*   ei    = (const int*)d_in[1];
    const int*   batch = (const int*)d_in[2];
    const float* W1r = (const float*)d_in[3];
    const float* W1n = (const float*)d_in[4];
    const float* b1  = (const float*)d_in[5];
    const float* W2r = (const float*)d_in[6];
    const float* W2n = (const float*)d_in[7];
    const float* b2  = (const float*)d_in[8];
    const float* W3r = (const float*)d_in[9];
    const float* W3n = (const float*)d_in[10];
    const float* b3  = (const float*)d_in[11];
    const float* Wl  = (const float*)d_in[12];
    const float* bl  = (const float*)d_in[13];
    float* out = (float*)d_out;

    const int* src = ei;
    const int* dst = ei + N_EDGES;

    char* base = (char*)d_ws;
    size_t off = 0;
    auto alloc = [&](size_t bytes) { char* p = base + off; off += (bytes + 255) & ~(size_t)255; return p; };
    u16* x_bf = (u16*)alloc((size_t)N_NODES * IN_CH * 2);
    u16* hA   = (u16*)alloc((size_t)N_NODES * HID * 2);
    u16* hB   = (u16*)alloc((size_t)N_NODES * HID * 2);
    u16* agg  = (u16*)alloc((size_t)N_NODES * HID * 2);
    u16* wt1r = (u16*)alloc((size_t)HID * IN_CH * 2);
    u16* wt1n = (u16*)alloc((size_t)HID * IN_CH * 2);
    u16* wt2r = (u16*)alloc((size_t)HID * HID * 2);
    u16* wt2n = (u16*)alloc((size_t)HID * HID * 2);
    u16* wt3r = (u16*)alloc((size_t)HID * HID * 2);
    u16* wt3n = (u16*)alloc((size_t)HID * HID * 2);
    float* partial = (float*)alloc((size_t)N_GRAPHS * 8 * HID * 4);
    float* pooled  = (float*)alloc((size_t)N_GRAPHS * HID * 4);
    int* deg       = (int*)alloc((size_t)N_NODES * 4);
    int* row_start = (int*)alloc((size_t)(N_NODES + 1) * 4);
    int* cursor    = (int*)alloc((size_t)N_NODES * 4);
    int* esrc      = (int*)alloc((size_t)N_EDGES * 4);
    int* bsum      = (int*)alloc((size_t)SCAN_BLOCKS * 4);
    int* boff      = (int*)alloc((size_t)SCAN_BLOCKS * 4);

    const int EB = (N_EDGES + 255) / 256;

    // ---- CSR build ----
    hipMemsetAsync(deg, 0, N_NODES * sizeof(int), stream);
    hist_kernel<<<EB, 256, 0, stream>>>(dst, deg);
    scan_p1<<<SCAN_BLOCKS, 256, 0, stream>>>(deg, bsum);
    scan_p2<<<1, 256, 0, stream>>>(bsum, boff, row_start);
    scan_p3<<<SCAN_BLOCKS, 256, 0, stream>>>(deg, boff, row_start, cursor);
    fill_kernel<<<EB, 256, 0, stream>>>(src, dst, cursor, esrc);

    // ---- conversions ----
    cvt_x_kernel<<<(N_NODES * (IN_CH / 8) + 255) / 256, 256, 0, stream>>>(x, x_bf);
    twt_kernel<<<(2 * IN_CH * HID + 255) / 256, 256, 0, stream>>>(
        W1r, W1n, nullptr, nullptr, wt1r, wt1n, nullptr, nullptr, IN_CH, 2);
    twt_kernel<<<(4 * HID * HID + 255) / 256, 256, 0, stream>>>(
        W2r, W2n, W3r, W3n, wt2r, wt2n, wt3r, wt3n, HID, 4);

    // ---- layer 1 (K=128, relu) ----
    gather_bf<IN_CH><<<(N_NODES * (IN_CH / 8) / 256) + 1, 256, 0, stream>>>(x_bf, row_start, esrc, agg);
    mfma_gemm<1><<<GEMM_WG, 256, 0, stream>>>(x_bf, agg, wt1r, wt1n, b1, hA, N_NODES, IN_CH);

    // ---- layer 2 (K=256, relu) ----
    gather_bf<HID><<<(N_NODES * (HID / 8) / 256) + 1, 256, 0, stream>>>(hA, row_start, esrc, agg);
    mfma_gemm<1><<<GEMM_WG, 256, 0, stream>>>(hA, agg, wt2r, wt2n, b2, hB, N_NODES, HID);

    // ---- layer 3 (K=256, no relu) ----
    gather_bf<HID><<<(N_NODES * (HID / 8) / 256) + 1, 256, 0, stream>>>(hB, row_start, esrc, agg);
    mfma_gemm<0><<<GEMM_WG, 256, 0, stream>>>(hB, agg, wt3r, wt3n, b3, hA, N_NODES, HID);

    // ---- pool + classifier ----
    pool1_kernel<<<N_GRAPHS * 8, HID, 0, stream>>>(hA, batch, partial);
    pool2_kernel<<<N_GRAPHS, HID, 0, stream>>>(partial, batch, pooled);
    final_kernel<<<N_GRAPHS, HID, 0, stream>>>(pooled, Wl, bl, out);
}

// Round 8
// 375.803 us; speedup vs baseline: 1.3478x; 1.0958x over previous
//
#include <hip/hip_runtime.h>
#include <stdint.h>

#define N_NODES 50000
#define N_EDGES 800000
#define IN_CH 128
#define HID 256
#define N_GRAPHS 64
#define N_CLASSES 10

#define SCAN_BLOCKS ((N_NODES + 255) / 256)   // 196
#define GEMM_MT ((N_NODES + 127) / 128)       // 391 row tiles
#define GEMM_WG (GEMM_MT * 2)                 // 782 blocks (2 col tiles)
#define NB ((N_NODES + 127) / 128)            // 391 dst buckets (128 nodes each)
#define EPB 4096                              // edges per bin_pass block

typedef unsigned short u16;
typedef __attribute__((ext_vector_type(8))) short short8;
typedef __attribute__((ext_vector_type(4))) float f32x4;

__device__ __forceinline__ float bf2f(uint32_t u) {
    union { uint32_t i; float f; } v; v.i = u << 16; return v.f;
}
__device__ __forceinline__ uint32_t f2bf(float f) {
    union { float f; uint32_t i; } v; v.f = f;
    return (v.i + 0x7FFFu + ((v.i >> 16) & 1u)) >> 16;   // RNE
}

// ===========================================================================
// CSR build: hist -> 3-phase scan -> counting-sort (bin + debin)
// ===========================================================================
__global__ void hist_kernel(const int* __restrict__ dst, int* __restrict__ deg)
{
    int e = blockIdx.x * blockDim.x + threadIdx.x;
    if (e < N_EDGES) atomicAdd(&deg[dst[e]], 1);
}

__global__ void __launch_bounds__(256) scan_p1(const int* __restrict__ deg, int* __restrict__ bsum)
{
    __shared__ int buf[256];
    int i = blockIdx.x * 256 + threadIdx.x;
    int v = (i < N_NODES) ? deg[i] : 0;
    buf[threadIdx.x] = v;
    __syncthreads();
    #pragma unroll
    for (int off = 128; off > 0; off >>= 1) {
        if (threadIdx.x < off) buf[threadIdx.x] += buf[threadIdx.x + off];
        __syncthreads();
    }
    if (threadIdx.x == 0) bsum[blockIdx.x] = buf[0];
}

__global__ void __launch_bounds__(256) scan_p2(const int* __restrict__ bsum,
                                               int* __restrict__ boff,
                                               int* __restrict__ row_start)
{
    __shared__ int buf[256];
    int t = threadIdx.x;
    int v = (t < SCAN_BLOCKS) ? bsum[t] : 0;
    buf[t] = v;
    __syncthreads();
    #pragma unroll
    for (int off = 1; off < 256; off <<= 1) {
        int a = (t >= off) ? buf[t - off] : 0;
        __syncthreads();
        buf[t] += a;
        __syncthreads();
    }
    if (t < SCAN_BLOCKS) boff[t] = buf[t] - v;
    if (t == 255) row_start[N_NODES] = buf[255];
}

__global__ void __launch_bounds__(256) scan_p3(const int* __restrict__ deg,
                                               const int* __restrict__ boff,
                                               int* __restrict__ row_start)
{
    __shared__ int buf[256];
    int t = threadIdx.x;
    int i = blockIdx.x * 256 + t;
    int v = (i < N_NODES) ? deg[i] : 0;
    buf[t] = v;
    __syncthreads();
    #pragma unroll
    for (int off = 1; off < 256; off <<= 1) {
        int a = (t >= off) ? buf[t - off] : 0;
        __syncthreads();
        buf[t] += a;
        __syncthreads();
    }
    if (i < N_NODES)
        row_start[i] = boff[blockIdx.x] + buf[t] - v;
}

__global__ void init_bcur(const int* __restrict__ row_start, int* __restrict__ gcur)
{
    int b = blockIdx.x * blockDim.x + threadIdx.x;
    if (b < NB) gcur[b] = row_start[b * 128];
}

// counting-sort pass 1: bin edges into 391 dst-buckets.
// Block reserves contiguous chunks per bucket (1 global atomic per bucket per
// block), so concurrent writes form contiguous runs -> write sectors fill.
__global__ void __launch_bounds__(512) bin_pass(const int* __restrict__ src,
                                                const int* __restrict__ dst,
                                                int* __restrict__ gcur,
                                                uint32_t* __restrict__ tmp)
{
    __shared__ int hist[NB];
    __shared__ int base[NB];
    int t = threadIdx.x;
    for (int i = t; i < NB; i += 512) hist[i] = 0;
    __syncthreads();
    const int e0 = blockIdx.x * EPB;
    int b_[8], s_[8], d_[8];
    #pragma unroll
    for (int k = 0; k < 8; ++k) {
        int e = e0 + k * 512 + t;
        if (e < N_EDGES) {
            int d = dst[e];
            b_[k] = d >> 7;
            d_[k] = d & 127;
            s_[k] = src[e];
            atomicAdd(&hist[b_[k]], 1);
        } else b_[k] = -1;
    }
    __syncthreads();
    for (int i = t; i < NB; i += 512) {
        int c = hist[i];
        base[i] = c ? atomicAdd(&gcur[i], c) : 0;
        hist[i] = 0;
    }
    __syncthreads();
    #pragma unroll
    for (int k = 0; k < 8; ++k) {
        if (b_[k] >= 0) {
            int r = atomicAdd(&hist[b_[k]], 1);
            tmp[base[b_[k]] + r] = ((uint32_t)s_[k] << 7) | (uint32_t)d_[k];
        }
    }
}

// counting-sort pass 2: within each bucket, scatter to exact per-dst segments.
// Writes confined to the bucket's ~8 KB esrc window (L2-resident).
__global__ void __launch_bounds__(256) debin_pass(const uint32_t* __restrict__ tmp,
                                                  const int* __restrict__ row_start,
                                                  int* __restrict__ esrc)
{
    __shared__ int lcur[128];
    const int b = blockIdx.x;
    const int n0 = b * 128;
    const int n1 = min(n0 + 128, N_NODES);
    const int t = threadIdx.x;
    if (t < n1 - n0) lcur[t] = row_start[n0 + t];
    const int start = row_start[n0];
    const int end = row_start[n1];
    __syncthreads();
    for (int p = start + t; p < end; p += 256) {
        uint32_t v = tmp[p];
        int dl = (int)(v & 127u);
        int s  = (int)(v >> 7);
        int pos = atomicAdd(&lcur[dl], 1);
        esrc[pos] = s;
    }
}

// ===========================================================================
// fp32 -> bf16 conversions
// ===========================================================================
__global__ void cvt_x_kernel(const float* __restrict__ x, u16* __restrict__ xb)
{
    int id = blockIdx.x * blockDim.x + threadIdx.x;
    if (id >= N_NODES * (IN_CH / 8)) return;
    const float4 a = *reinterpret_cast<const float4*>(x + (size_t)id * 8);
    const float4 b = *reinterpret_cast<const float4*>(x + (size_t)id * 8 + 4);
    uint4 o;
    o.x = f2bf(a.x) | (f2bf(a.y) << 16);
    o.y = f2bf(a.z) | (f2bf(a.w) << 16);
    o.z = f2bf(b.x) | (f2bf(b.y) << 16);
    o.w = f2bf(b.z) | (f2bf(b.w) << 16);
    *reinterpret_cast<uint4*>(xb + (size_t)id * 8) = o;
}

__global__ void twt_kernel(const float* W0, const float* W1, const float* W2, const float* W3,
                           u16* o0, u16* o1, u16* o2, u16* o3, int K, int nmat)
{
    int id = blockIdx.x * blockDim.x + threadIdx.x;
    int per = K * HID;
    int m = id / per;
    if (m >= nmat) return;
    int r = id % per;
    int k = r / HID, n = r % HID;
    const float* W = (m == 0) ? W0 : (m == 1) ? W1 : (m == 2) ? W2 : W3;
    u16* O = (m == 0) ? o0 : (m == 1) ? o1 : (m == 2) ? o2 : o3;
    O[(size_t)n * K + k] = (u16)f2bf(W[r]);
}

// ===========================================================================
// agg[i,:] = sum_{j in in(i)} feat[j,:]  — bf16, fp32 acc, 4-deep unroll
// ===========================================================================
template<int D>
__global__ void __launch_bounds__(256)
gather_bf(const u16* __restrict__ feat, const int* __restrict__ row_start,
          const int* __restrict__ esrc, u16* __restrict__ agg)
{
    constexpr int GS = D / 8;
    constexpr int NPB = 256 / GS;
    int node = blockIdx.x * NPB + threadIdx.x / GS;
    int lane = threadIdx.x % GS;
    if (node >= N_NODES) return;
    const int s = row_start[node], e = row_start[node + 1];
    float acc[8] = {0.f, 0.f, 0.f, 0.f, 0.f, 0.f, 0.f, 0.f};
    const u16* fp = feat + lane * 8;

    auto add = [&](uint4 v) {
        acc[0] += bf2f(v.x & 0xFFFF); acc[1] += bf2f(v.x >> 16);
        acc[2] += bf2f(v.y & 0xFFFF); acc[3] += bf2f(v.y >> 16);
        acc[4] += bf2f(v.z & 0xFFFF); acc[5] += bf2f(v.z >> 16);
        acc[6] += bf2f(v.w & 0xFFFF); acc[7] += bf2f(v.w >> 16);
    };

    int j = s;
    for (; j + 3 < e; j += 4) {
        int s0 = esrc[j], s1 = esrc[j + 1], s2 = esrc[j + 2], s3 = esrc[j + 3];
        uint4 v0 = *reinterpret_cast<const uint4*>(fp + (size_t)s0 * D);
        uint4 v1 = *reinterpret_cast<const uint4*>(fp + (size_t)s1 * D);
        uint4 v2 = *reinterpret_cast<const uint4*>(fp + (size_t)s2 * D);
        uint4 v3 = *reinterpret_cast<const uint4*>(fp + (size_t)s3 * D);
        add(v0); add(v1); add(v2); add(v3);
    }
    for (; j < e; ++j) {
        uint4 v0 = *reinterpret_cast<const uint4*>(fp + (size_t)esrc[j] * D);
        add(v0);
    }
    uint4 o;
    o.x = f2bf(acc[0]) | (f2bf(acc[1]) << 16);
    o.y = f2bf(acc[2]) | (f2bf(acc[3]) << 16);
    o.z = f2bf(acc[4]) | (f2bf(acc[5]) << 16);
    o.w = f2bf(acc[6]) | (f2bf(acc[7]) << 16);
    *reinterpret_cast<uint4*>(agg + (size_t)node * D + lane * 8) = o;
}

// ===========================================================================
// C[m,n] = act( A1@W1 + A2@W2 + bias )   — bf16 MFMA, fp32 acc, bf16 out
// ===========================================================================
template<int RELU>
__global__ void __launch_bounds__(256)
mfma_gemm(const u16* __restrict__ A1, const u16* __restrict__ A2,
          const u16* __restrict__ B1t, const u16* __restrict__ B2t,
          const float* __restrict__ bias,
          u16* __restrict__ C,
          int M, int K)
{
    __shared__ __align__(16) u16 As[128][40];
    __shared__ __align__(16) u16 Bs[128][40];

    const int orig = blockIdx.x;
    const int q = GEMM_WG / 8, r = GEMM_WG % 8;
    const int xcd = orig % 8;
    const int wg = (xcd < r ? xcd * (q + 1) : r * (q + 1) + (xcd - r) * q) + orig / 8;

    const int tid = threadIdx.x;
    const int bm = (wg >> 1) * 128;
    const int bn = (wg & 1) * 128;
    const int w  = tid >> 6;
    const int wm = (w >> 1) * 64;
    const int wn = (w & 1) * 64;
    const int l  = tid & 63;
    const int lr = l & 15;
    const int kb = (l >> 4) * 8;

    f32x4 acc[4][4];
    #pragma unroll
    for (int i = 0; i < 4; ++i)
        #pragma unroll
        for (int j = 0; j < 4; ++j)
            acc[i][j] = (f32x4){0.f, 0.f, 0.f, 0.f};

    const int row_s = tid >> 2;
    const int c8    = (tid & 3) * 8;

    for (int mat = 0; mat < 2; ++mat) {
        const u16* __restrict__ Ag = mat ? A2 : A1;
        const u16* __restrict__ Bg = mat ? B2t : B1t;
        for (int k0 = 0; k0 < K; k0 += 32) {
            #pragma unroll
            for (int it = 0; it < 2; ++it) {
                int row = row_s + it * 64;
                uint4 va = make_uint4(0u, 0u, 0u, 0u);
                int gr = bm + row;
                if (gr < M)
                    va = *reinterpret_cast<const uint4*>(Ag + (size_t)gr * K + k0 + c8);
                *reinterpret_cast<uint4*>(&As[row][c8]) = va;
                uint4 vb = *reinterpret_cast<const uint4*>(Bg + (size_t)(bn + row) * K + k0 + c8);
                *reinterpret_cast<uint4*>(&Bs[row][c8]) = vb;
            }
            __syncthreads();
            short8 af[4], bfr[4];
            #pragma unroll
            for (int f = 0; f < 4; ++f) {
                af[f]  = *reinterpret_cast<const short8*>(&As[wm + f * 16 + lr][kb]);
                bfr[f] = *reinterpret_cast<const short8*>(&Bs[wn + f * 16 + lr][kb]);
            }
            #pragma unroll
            for (int fm = 0; fm < 4; ++fm)
                #pragma unroll
                for (int fn = 0; fn < 4; ++fn)
                    acc[fm][fn] = __builtin_amdgcn_mfma_f32_16x16x32_bf16(
                        af[fm], bfr[fn], acc[fm][fn], 0, 0, 0);
            __syncthreads();
        }
    }

    const int r4 = (l >> 4) * 4;
    #pragma unroll
    for (int fm = 0; fm < 4; ++fm) {
        #pragma unroll
        for (int rr = 0; rr < 4; ++rr) {
            int row = bm + wm + fm * 16 + r4 + rr;
            if (row >= M) continue;
            #pragma unroll
            for (int fn = 0; fn < 4; ++fn) {
                int col = bn + wn + fn * 16 + lr;
                float v = acc[fm][fn][rr] + bias[col];
                if (RELU) v = fmaxf(v, 0.f);
                C[(size_t)row * HID + col] = (u16)f2bf(v);
            }
        }
    }
}

// ===========================================================================
// Pooling (batch sorted): inline binary search, two-stage mean
// ===========================================================================
__device__ __forceinline__ int lower_bound_g(const int* __restrict__ batch, int g)
{
    int lo = 0, hi = N_NODES;
    while (lo < hi) {
        int mid = (lo + hi) >> 1;
        if (batch[mid] < g) lo = mid + 1; else hi = mid;
    }
    return lo;
}

__global__ void pool1_kernel(const u16* __restrict__ h, const int* __restrict__ batch,
                             float* __restrict__ partial)
{
    int g = blockIdx.x >> 3;
    int c = blockIdx.x & 7;
    int t = threadIdx.x;      // 256
    int s = lower_bound_g(batch, g);
    int e = lower_bound_g(batch, g + 1);
    int cnt = e - s;
    int a = s + (int)(((long long)cnt * c) >> 3);
    int b = s + (int)(((long long)cnt * (c + 1)) >> 3);
    float acc = 0.f;
    for (int i = a; i < b; ++i)
        acc += bf2f(h[(size_t)i * HID + t]);
    partial[(size_t)blockIdx.x * HID + t] = acc;
}

__global__ void pool2_kernel(const float* __restrict__ partial, const int* __restrict__ batch,
                             float* __restrict__ pooled)
{
    int g = blockIdx.x;
    int t = threadIdx.x;
    float acc = 0.f;
    #pragma unroll
    for (int c = 0; c < 8; ++c)
        acc += partial[(size_t)(g * 8 + c) * HID + t];
    float cnt = fmaxf((float)(lower_bound_g(batch, g + 1) - lower_bound_g(batch, g)), 1.f);
    pooled[g * HID + t] = acc / cnt;
}

__global__ void final_kernel(const float* __restrict__ pooled,
                             const float* __restrict__ W_lin,
                             const float* __restrict__ b_lin,
                             float* __restrict__ out)
{
    __shared__ float v[HID];
    int g = blockIdx.x;
    int t = threadIdx.x;
    v[t] = pooled[g * HID + t];
    __syncthreads();
    if (t < N_CLASSES) {
        float s = b_lin[t];
        for (int k = 0; k < HID; ++k)
            s += v[k] * W_lin[k * N_CLASSES + t];
        out[g * N_CLASSES + t] = s;
    }
}

// ===========================================================================
extern "C" void kernel_launch(void* const* d_in, const int* in_sizes, int n_in,
                              void* d_out, int out_size, void* d_ws, size_t ws_size,
                              hipStream_t stream)
{
    const float* x     = (const float*)d_in[0];
    const int*   ei    = (const int*)d_in[1];
    const int*   batch = (const int*)d_in[2];
    const float* W1r = (const float*)d_in[3];
    const float* W1n = (const float*)d_in[4];
    const float* b1  = (const float*)d_in[5];
    const float* W2r = (const float*)d_in[6];
    const float* W2n = (const float*)d_in[7];
    const float* b2  = (const float*)d_in[8];
    const float* W3r = (const float*)d_in[9];
    const float* W3n = (const float*)d_in[10];
    const float* b3  = (const float*)d_in[11];
    const float* Wl  = (const float*)d_in[12];
    const float* bl  = (const float*)d_in[13];
    float* out = (float*)d_out;

    const int* src = ei;
    const int* dst = ei + N_EDGES;

    char* base = (char*)d_ws;
    size_t off = 0;
    auto alloc = [&](size_t bytes) { char* p = base + off; off += (bytes + 255) & ~(size_t)255; return p; };
    u16* x_bf = (u16*)alloc((size_t)N_NODES * IN_CH * 2);
    u16* hA   = (u16*)alloc((size_t)N_NODES * HID * 2);
    u16* hB   = (u16*)alloc((size_t)N_NODES * HID * 2);
    u16* agg  = (u16*)alloc((size_t)N_NODES * HID * 2);
    u16* wt1r = (u16*)alloc((size_t)HID * IN_CH * 2);
    u16* wt1n = (u16*)alloc((size_t)HID * IN_CH * 2);
    u16* wt2r = (u16*)alloc((size_t)HID * HID * 2);
    u16* wt2n = (u16*)alloc((size_t)HID * HID * 2);
    u16* wt3r = (u16*)alloc((size_t)HID * HID * 2);
    u16* wt3n = (u16*)alloc((size_t)HID * HID * 2);
    float* partial = (float*)alloc((size_t)N_GRAPHS * 8 * HID * 4);
    float* pooled  = (float*)alloc((size_t)N_GRAPHS * HID * 4);
    int* deg       = (int*)alloc((size_t)N_NODES * 4);
    int* row_start = (int*)alloc((size_t)(N_NODES + 1) * 4);
    int* esrc      = (int*)alloc((size_t)N_EDGES * 4);
    uint32_t* tmp  = (uint32_t*)alloc((size_t)N_EDGES * 4);
    int* gcur      = (int*)alloc((size_t)NB * 4);
    int* bsum      = (int*)alloc((size_t)SCAN_BLOCKS * 4);
    int* boff      = (int*)alloc((size_t)SCAN_BLOCKS * 4);

    const int EB = (N_EDGES + 255) / 256;

    // ---- CSR build (counting sort, no random 4B scatters) ----
    hipMemsetAsync(deg, 0, N_NODES * sizeof(int), stream);
    hist_kernel<<<EB, 256, 0, stream>>>(dst, deg);
    scan_p1<<<SCAN_BLOCKS, 256, 0, stream>>>(deg, bsum);
    scan_p2<<<1, 256, 0, stream>>>(bsum, boff, row_start);
    scan_p3<<<SCAN_BLOCKS, 256, 0, stream>>>(deg, boff, row_start);
    init_bcur<<<(NB + 255) / 256, 256, 0, stream>>>(row_start, gcur);
    bin_pass<<<(N_EDGES + EPB - 1) / EPB, 512, 0, stream>>>(src, dst, gcur, tmp);
    debin_pass<<<NB, 256, 0, stream>>>(tmp, row_start, esrc);

    // ---- conversions ----
    cvt_x_kernel<<<(N_NODES * (IN_CH / 8) + 255) / 256, 256, 0, stream>>>(x, x_bf);
    twt_kernel<<<(2 * IN_CH * HID + 255) / 256, 256, 0, stream>>>(
        W1r, W1n, nullptr, nullptr, wt1r, wt1n, nullptr, nullptr, IN_CH, 2);
    twt_kernel<<<(4 * HID * HID + 255) / 256, 256, 0, stream>>>(
        W2r, W2n, W3r, W3n, wt2r, wt2n, wt3r, wt3n, HID, 4);

    // ---- layer 1 (K=128, relu) ----
    gather_bf<IN_CH><<<(N_NODES * (IN_CH / 8) / 256) + 1, 256, 0, stream>>>(x_bf, row_start, esrc, agg);
    mfma_gemm<1><<<GEMM_WG, 256, 0, stream>>>(x_bf, agg, wt1r, wt1n, b1, hA, N_NODES, IN_CH);

    // ---- layer 2 (K=256, relu) ----
    gather_bf<HID><<<(N_NODES * (HID / 8) / 256) + 1, 256, 0, stream>>>(hA, row_start, esrc, agg);
    mfma_gemm<1><<<GEMM_WG, 256, 0, stream>>>(hA, agg, wt2r, wt2n, b2, hB, N_NODES, HID);

    // ---- layer 3 (K=256, no relu) ----
    gather_bf<HID><<<(N_NODES * (HID / 8) / 256) + 1, 256, 0, stream>>>(hB, row_start, esrc, agg);
    mfma_gemm<0><<<GEMM_WG, 256, 0, stream>>>(hB, agg, wt3r, wt3n, b3, hA, N_NODES, HID);

    // ---- pool + classifier ----
    pool1_kernel<<<N_GRAPHS * 8, HID, 0, stream>>>(hA, batch, partial);
    pool2_kernel<<<N_GRAPHS, HID, 0, stream>>>(partial, batch, pooled);
    final_kernel<<<N_GRAPHS, HID, 0, stream>>>(pooled, Wl, bl, out);
}

// Round 9
// 331.613 us; speedup vs baseline: 1.5274x; 1.1333x over previous
//
#include <hip/hip_runtime.h>
#include <stdint.h>

#define N_NODES 50000
#define N_EDGES 800000
#define IN_CH 128
#define HID 256
#define N_GRAPHS 64
#define N_CLASSES 10

#define GEMM_MT ((N_NODES + 127) / 128)       // 391 row tiles
#define GEMM_WG (GEMM_MT * 2)                 // 782 blocks (2 col tiles)
#define NB ((N_NODES + 127) / 128)            // 391 dst buckets (128 nodes each)
#define EPB 4096                              // edges per bin_pass block
#define CAP 4096                              // slots per bucket (mean 2048, 45 sigma)

typedef unsigned short u16;
typedef __attribute__((ext_vector_type(8))) short short8;
typedef __attribute__((ext_vector_type(4))) float f32x4;

__device__ __forceinline__ float bf2f(uint32_t u) {
    union { uint32_t i; float f; } v; v.i = u << 16; return v.f;
}
__device__ __forceinline__ uint32_t f2bf(float f) {
    union { float f; uint32_t i; } v; v.f = f;
    return (v.i + 0x7FFFu + ((v.i >> 16) & 1u)) >> 16;   // RNE
}

// ===========================================================================
// CSR build: bin (fixed-capacity buckets) -> bucket scan -> debin
// ===========================================================================
// pass 1: bin edges into 391 dst-buckets at tmp[b*CAP ...]; gcnt must be 0.
__global__ void __launch_bounds__(512) bin_pass(const int* __restrict__ src,
                                                const int* __restrict__ dst,
                                                int* __restrict__ gcnt,
                                                uint32_t* __restrict__ tmp)
{
    __shared__ int hist[NB];
    __shared__ int base[NB];
    int t = threadIdx.x;
    for (int i = t; i < NB; i += 512) hist[i] = 0;
    __syncthreads();
    const int e0 = blockIdx.x * EPB;
    int b_[8], s_[8], d_[8];
    #pragma unroll
    for (int k = 0; k < 8; ++k) {
        int e = e0 + k * 512 + t;
        if (e < N_EDGES) {
            int d = dst[e];
            b_[k] = d >> 7;
            d_[k] = d & 127;
            s_[k] = src[e];
            atomicAdd(&hist[b_[k]], 1);
        } else b_[k] = -1;
    }
    __syncthreads();
    for (int i = t; i < NB; i += 512) {
        int c = hist[i];
        base[i] = c ? atomicAdd(&gcnt[i], c) : 0;
        hist[i] = 0;
    }
    __syncthreads();
    #pragma unroll
    for (int k = 0; k < 8; ++k) {
        if (b_[k] >= 0) {
            int r = atomicAdd(&hist[b_[k]], 1);
            int pos = base[b_[k]] + r;
            if (pos < CAP)
                tmp[(size_t)b_[k] * CAP + pos] = ((uint32_t)s_[k] << 7) | (uint32_t)d_[k];
        }
    }
}

// pass 2: single block scans 391 bucket counts -> exclusive boff
__global__ void __launch_bounds__(512) bucket_scan(const int* __restrict__ gcnt,
                                                   int* __restrict__ boff,
                                                   int* __restrict__ row_start)
{
    __shared__ int buf[512];
    int t = threadIdx.x;
    int v = (t < NB) ? gcnt[t] : 0;
    buf[t] = v;
    __syncthreads();
    #pragma unroll
    for (int off = 1; off < 512; off <<= 1) {
        int a = (t >= off) ? buf[t - off] : 0;
        __syncthreads();
        buf[t] += a;
        __syncthreads();
    }
    if (t < NB) boff[t] = buf[t] - v;
    if (t == 0) row_start[N_NODES] = N_EDGES;
}

// pass 3: per bucket: LDS histogram of dst-local -> local scan -> row_start,
// then scatter esrc within the bucket's ~8 KB window (L2-resident).
__global__ void __launch_bounds__(256) debin2(const uint32_t* __restrict__ tmp,
                                              const int* __restrict__ gcnt,
                                              const int* __restrict__ boff,
                                              int* __restrict__ row_start,
                                              int* __restrict__ esrc)
{
    __shared__ int h[128];
    __shared__ int pre[128];
    __shared__ int cur[128];
    const int b = blockIdx.x;
    const int n0 = b * 128;
    const int nn = min(128, N_NODES - n0);
    const int t = threadIdx.x;
    const int cnt = min(gcnt[b], CAP);
    const int bb = boff[b];
    const uint32_t* te = tmp + (size_t)b * CAP;

    if (t < 128) h[t] = 0;
    __syncthreads();
    for (int p = t; p < cnt; p += 256)
        atomicAdd(&h[te[p] & 127u], 1);
    __syncthreads();
    if (t < 128) pre[t] = h[t];
    __syncthreads();
    #pragma unroll
    for (int off = 1; off < 128; off <<= 1) {
        int a = (t >= off && t < 128) ? pre[t - off] : 0;
        __syncthreads();
        if (t < 128) pre[t] += a;
        __syncthreads();
    }
    if (t < nn) {
        int rs = bb + pre[t] - h[t];   // exclusive
        row_start[n0 + t] = rs;
        cur[t] = rs;
    }
    __syncthreads();
    for (int p = t; p < cnt; p += 256) {
        uint32_t v = te[p];
        int pos = atomicAdd(&cur[v & 127u], 1);
        esrc[pos] = (int)(v >> 7);
    }
}

// ===========================================================================
// fused conversions: x -> bf16 (vectorized) + 6 weight transposes
// ===========================================================================
#define XB 3125   // N_NODES*IN_CH/8/256
__global__ void __launch_bounds__(256)
cvt_all(const float* __restrict__ x, u16* __restrict__ xb,
        const float* __restrict__ W1r, const float* __restrict__ W1n,
        const float* __restrict__ W2r, const float* __restrict__ W2n,
        const float* __restrict__ W3r, const float* __restrict__ W3n,
        u16* __restrict__ o1r, u16* __restrict__ o1n,
        u16* __restrict__ o2r, u16* __restrict__ o2n,
        u16* __restrict__ o3r, u16* __restrict__ o3n)
{
    if (blockIdx.x < XB) {
        int id = blockIdx.x * 256 + threadIdx.x;
        const float4 a = *reinterpret_cast<const float4*>(x + (size_t)id * 8);
        const float4 b = *reinterpret_cast<const float4*>(x + (size_t)id * 8 + 4);
        uint4 o;
        o.x = f2bf(a.x) | (f2bf(a.y) << 16);
        o.y = f2bf(a.z) | (f2bf(a.w) << 16);
        o.z = f2bf(b.x) | (f2bf(b.y) << 16);
        o.w = f2bf(b.z) | (f2bf(b.w) << 16);
        *reinterpret_cast<uint4*>(xb + (size_t)id * 8) = o;
        return;
    }
    int id = (blockIdx.x - XB) * 256 + threadIdx.x;   // 0..327679
    if (id < 65536) {                                  // W1: [128][256]
        int m = id >> 15;
        int r = id & 32767;
        int k = r >> 8, n = r & 255;
        const float* W = m ? W1n : W1r;
        u16* O = m ? o1n : o1r;
        O[n * 128 + k] = (u16)f2bf(W[r]);
    } else {                                           // W2/W3: [256][256]
        id -= 65536;
        int m = id >> 16;
        int r = id & 65535;
        int k = r >> 8, n = r & 255;
        const float* W = (m == 0) ? W2r : (m == 1) ? W2n : (m == 2) ? W3r : W3n;
        u16* O = (m == 0) ? o2r : (m == 1) ? o2n : (m == 2) ? o3r : o3n;
        O[n * 256 + k] = (u16)f2bf(W[r]);
    }
}

// ===========================================================================
// agg[i,:] = sum_{j in in(i)} feat[j,:]  — bf16, fp32 acc, 4-deep unroll
// ===========================================================================
template<int D>
__global__ void __launch_bounds__(256)
gather_bf(const u16* __restrict__ feat, const int* __restrict__ row_start,
          const int* __restrict__ esrc, u16* __restrict__ agg)
{
    constexpr int GS = D / 8;
    constexpr int NPB = 256 / GS;
    int node = blockIdx.x * NPB + threadIdx.x / GS;
    int lane = threadIdx.x % GS;
    if (node >= N_NODES) return;
    const int s = row_start[node], e = row_start[node + 1];
    float acc[8] = {0.f, 0.f, 0.f, 0.f, 0.f, 0.f, 0.f, 0.f};
    const u16* fp = feat + lane * 8;

    auto add = [&](uint4 v) {
        acc[0] += bf2f(v.x & 0xFFFF); acc[1] += bf2f(v.x >> 16);
        acc[2] += bf2f(v.y & 0xFFFF); acc[3] += bf2f(v.y >> 16);
        acc[4] += bf2f(v.z & 0xFFFF); acc[5] += bf2f(v.z >> 16);
        acc[6] += bf2f(v.w & 0xFFFF); acc[7] += bf2f(v.w >> 16);
    };

    int j = s;
    for (; j + 3 < e; j += 4) {
        int s0 = esrc[j], s1 = esrc[j + 1], s2 = esrc[j + 2], s3 = esrc[j + 3];
        uint4 v0 = *reinterpret_cast<const uint4*>(fp + (size_t)s0 * D);
        uint4 v1 = *reinterpret_cast<const uint4*>(fp + (size_t)s1 * D);
        uint4 v2 = *reinterpret_cast<const uint4*>(fp + (size_t)s2 * D);
        uint4 v3 = *reinterpret_cast<const uint4*>(fp + (size_t)s3 * D);
        add(v0); add(v1); add(v2); add(v3);
    }
    for (; j < e; ++j) {
        uint4 v0 = *reinterpret_cast<const uint4*>(fp + (size_t)esrc[j] * D);
        add(v0);
    }
    uint4 o;
    o.x = f2bf(acc[0]) | (f2bf(acc[1]) << 16);
    o.y = f2bf(acc[2]) | (f2bf(acc[3]) << 16);
    o.z = f2bf(acc[4]) | (f2bf(acc[5]) << 16);
    o.w = f2bf(acc[6]) | (f2bf(acc[7]) << 16);
    *reinterpret_cast<uint4*>(agg + (size_t)node * D + lane * 8) = o;
}

// ===========================================================================
// C[m,n] = act( A1@W1 + A2@W2 + bias )   — bf16 MFMA, fp32 acc, bf16 out
// ===========================================================================
template<int RELU>
__global__ void __launch_bounds__(256)
mfma_gemm(const u16* __restrict__ A1, const u16* __restrict__ A2,
          const u16* __restrict__ B1t, const u16* __restrict__ B2t,
          const float* __restrict__ bias,
          u16* __restrict__ C,
          int M, int K)
{
    __shared__ __align__(16) u16 As[128][40];
    __shared__ __align__(16) u16 Bs[128][40];

    const int orig = blockIdx.x;
    const int q = GEMM_WG / 8, r = GEMM_WG % 8;
    const int xcd = orig % 8;
    const int wg = (xcd < r ? xcd * (q + 1) : r * (q + 1) + (xcd - r) * q) + orig / 8;

    const int tid = threadIdx.x;
    const int bm = (wg >> 1) * 128;
    const int bn = (wg & 1) * 128;
    const int w  = tid >> 6;
    const int wm = (w >> 1) * 64;
    const int wn = (w & 1) * 64;
    const int l  = tid & 63;
    const int lr = l & 15;
    const int kb = (l >> 4) * 8;

    f32x4 acc[4][4];
    #pragma unroll
    for (int i = 0; i < 4; ++i)
        #pragma unroll
        for (int j = 0; j < 4; ++j)
            acc[i][j] = (f32x4){0.f, 0.f, 0.f, 0.f};

    const int row_s = tid >> 2;
    const int c8    = (tid & 3) * 8;

    for (int mat = 0; mat < 2; ++mat) {
        const u16* __restrict__ Ag = mat ? A2 : A1;
        const u16* __restrict__ Bg = mat ? B2t : B1t;
        for (int k0 = 0; k0 < K; k0 += 32) {
            #pragma unroll
            for (int it = 0; it < 2; ++it) {
                int row = row_s + it * 64;
                uint4 va = make_uint4(0u, 0u, 0u, 0u);
                int gr = bm + row;
                if (gr < M)
                    va = *reinterpret_cast<const uint4*>(Ag + (size_t)gr * K + k0 + c8);
                *reinterpret_cast<uint4*>(&As[row][c8]) = va;
                uint4 vb = *reinterpret_cast<const uint4*>(Bg + (size_t)(bn + row) * K + k0 + c8);
                *reinterpret_cast<uint4*>(&Bs[row][c8]) = vb;
            }
            __syncthreads();
            short8 af[4], bfr[4];
            #pragma unroll
            for (int f = 0; f < 4; ++f) {
                af[f]  = *reinterpret_cast<const short8*>(&As[wm + f * 16 + lr][kb]);
                bfr[f] = *reinterpret_cast<const short8*>(&Bs[wn + f * 16 + lr][kb]);
            }
            #pragma unroll
            for (int fm = 0; fm < 4; ++fm)
                #pragma unroll
                for (int fn = 0; fn < 4; ++fn)
                    acc[fm][fn] = __builtin_amdgcn_mfma_f32_16x16x32_bf16(
                        af[fm], bfr[fn], acc[fm][fn], 0, 0, 0);
            __syncthreads();
        }
    }

    const int r4 = (l >> 4) * 4;
    #pragma unroll
    for (int fm = 0; fm < 4; ++fm) {
        #pragma unroll
        for (int rr = 0; rr < 4; ++rr) {
            int row = bm + wm + fm * 16 + r4 + rr;
            if (row >= M) continue;
            #pragma unroll
            for (int fn = 0; fn < 4; ++fn) {
                int col = bn + wn + fn * 16 + lr;
                float v = acc[fm][fn][rr] + bias[col];
                if (RELU) v = fmaxf(v, 0.f);
                C[(size_t)row * HID + col] = (u16)f2bf(v);
            }
        }
    }
}

// ===========================================================================
// Pooling (batch sorted): inline binary search, two-stage mean + classifier
// ===========================================================================
__device__ __forceinline__ int lower_bound_g(const int* __restrict__ batch, int g)
{
    int lo = 0, hi = N_NODES;
    while (lo < hi) {
        int mid = (lo + hi) >> 1;
        if (batch[mid] < g) lo = mid + 1; else hi = mid;
    }
    return lo;
}

__global__ void pool1_kernel(const u16* __restrict__ h, const int* __restrict__ batch,
                             float* __restrict__ partial)
{
    int g = blockIdx.x >> 3;
    int c = blockIdx.x & 7;
    int t = threadIdx.x;      // 256
    int s = lower_bound_g(batch, g);
    int e = lower_bound_g(batch, g + 1);
    int cnt = e - s;
    int a = s + (int)(((long long)cnt * c) >> 3);
    int b = s + (int)(((long long)cnt * (c + 1)) >> 3);
    float acc = 0.f;
    for (int i = a; i < b; ++i)
        acc += bf2f(h[(size_t)i * HID + t]);
    partial[(size_t)blockIdx.x * HID + t] = acc;
}

__global__ void pool2_final(const float* __restrict__ partial, const int* __restrict__ batch,
                            const float* __restrict__ W_lin, const float* __restrict__ b_lin,
                            float* __restrict__ out)
{
    __shared__ float v[HID];
    int g = blockIdx.x;
    int t = threadIdx.x;
    float acc = 0.f;
    #pragma unroll
    for (int c = 0; c < 8; ++c)
        acc += partial[(size_t)(g * 8 + c) * HID + t];
    float cnt = fmaxf((float)(lower_bound_g(batch, g + 1) - lower_bound_g(batch, g)), 1.f);
    v[t] = acc / cnt;
    __syncthreads();
    if (t < N_CLASSES) {
        float s = b_lin[t];
        for (int k = 0; k < HID; ++k)
            s += v[k] * W_lin[k * N_CLASSES + t];
        out[g * N_CLASSES + t] = s;
    }
}

// ===========================================================================
extern "C" void kernel_launch(void* const* d_in, const int* in_sizes, int n_in,
                              void* d_out, int out_size, void* d_ws, size_t ws_size,
                              hipStream_t stream)
{
    const float* x     = (const float*)d_in[0];
    const int*   ei    = (const int*)d_in[1];
    const int*   batch = (const int*)d_in[2];
    const float* W1r = (const float*)d_in[3];
    const float* W1n = (const float*)d_in[4];
    const float* b1  = (const float*)d_in[5];
    const float* W2r = (const float*)d_in[6];
    const float* W2n = (const float*)d_in[7];
    const float* b2  = (const float*)d_in[8];
    const float* W3r = (const float*)d_in[9];
    const float* W3n = (const float*)d_in[10];
    const float* b3  = (const float*)d_in[11];
    const float* Wl  = (const float*)d_in[12];
    const float* bl  = (const float*)d_in[13];
    float* out = (float*)d_out;

    const int* src = ei;
    const int* dst = ei + N_EDGES;

    char* base = (char*)d_ws;
    size_t off = 0;
    auto alloc = [&](size_t bytes) { char* p = base + off; off += (bytes + 255) & ~(size_t)255; return p; };
    u16* x_bf = (u16*)alloc((size_t)N_NODES * IN_CH * 2);
    u16* hA   = (u16*)alloc((size_t)N_NODES * HID * 2);
    u16* hB   = (u16*)alloc((size_t)N_NODES * HID * 2);
    u16* agg  = (u16*)alloc((size_t)N_NODES * HID * 2);
    u16* wt1r = (u16*)alloc((size_t)HID * IN_CH * 2);
    u16* wt1n = (u16*)alloc((size_t)HID * IN_CH * 2);
    u16* wt2r = (u16*)alloc((size_t)HID * HID * 2);
    u16* wt2n = (u16*)alloc((size_t)HID * HID * 2);
    u16* wt3r = (u16*)alloc((size_t)HID * HID * 2);
    u16* wt3n = (u16*)alloc((size_t)HID * HID * 2);
    float* partial = (float*)alloc((size_t)N_GRAPHS * 8 * HID * 4);
    int* row_start = (int*)alloc((size_t)(N_NODES + 1) * 4);
    int* esrc      = (int*)alloc((size_t)N_EDGES * 4);
    uint32_t* tmp  = (uint32_t*)alloc((size_t)NB * CAP * 4);
    int* gcnt      = (int*)alloc((size_t)NB * 4);
    int* boff      = (int*)alloc((size_t)NB * 4);

    // ---- CSR build (4 dispatches: memset + bin + scan + debin) ----
    hipMemsetAsync(gcnt, 0, NB * sizeof(int), stream);
    bin_pass<<<(N_EDGES + EPB - 1) / EPB, 512, 0, stream>>>(src, dst, gcnt, tmp);
    bucket_scan<<<1, 512, 0, stream>>>(gcnt, boff, row_start);
    debin2<<<NB, 256, 0, stream>>>(tmp, gcnt, boff, row_start, esrc);

    // ---- conversions (1 dispatch) ----
    cvt_all<<<XB + 1280, 256, 0, stream>>>(x, x_bf, W1r, W1n, W2r, W2n, W3r, W3n,
                                           wt1r, wt1n, wt2r, wt2n, wt3r, wt3n);

    // ---- layer 1 (K=128, relu) ----
    gather_bf<IN_CH><<<(N_NODES * (IN_CH / 8) / 256) + 1, 256, 0, stream>>>(x_bf, row_start, esrc, agg);
    mfma_gemm<1><<<GEMM_WG, 256, 0, stream>>>(x_bf, agg, wt1r, wt1n, b1, hA, N_NODES, IN_CH);

    // ---- layer 2 (K=256, relu) ----
    gather_bf<HID><<<(N_NODES * (HID / 8) / 256) + 1, 256, 0, stream>>>(hA, row_start, esrc, agg);
    mfma_gemm<1><<<GEMM_WG, 256, 0, stream>>>(hA, agg, wt2r, wt2n, b2, hB, N_NODES, HID);

    // ---- layer 3 (K=256, no relu) ----
    gather_bf<HID><<<(N_NODES * (HID / 8) / 256) + 1, 256, 0, stream>>>(hB, row_start, esrc, agg);
    mfma_gemm<0><<<GEMM_WG, 256, 0, stream>>>(hB, agg, wt3r, wt3n, b3, hA, N_NODES, HID);

    // ---- pool + classifier (2 dispatches) ----
    pool1_kernel<<<N_GRAPHS * 8, HID, 0, stream>>>(hA, batch, partial);
    pool2_final<<<N_GRAPHS, HID, 0, stream>>>(partial, batch, Wl, bl, out);
}

// Round 10
// 326.911 us; speedup vs baseline: 1.5494x; 1.0144x over previous
//
#include <hip/hip_runtime.h>
#include <stdint.h>

#define N_NODES 50000
#define N_EDGES 800000
#define IN_CH 128
#define HID 256
#define N_GRAPHS 64
#define N_CLASSES 10

#define GEMM_MT ((N_NODES + 127) / 128)       // 391 row tiles
#define GEMM_WG (GEMM_MT * 2)                 // 782 blocks (2 col tiles)
#define NB ((N_NODES + 127) / 128)            // 391 dst buckets (128 nodes each)
#define EPB 4096                              // edges per bin_pass block
#define CAP 4096                              // slots per bucket (mean 2048, 45 sigma)

typedef unsigned short u16;
typedef __attribute__((ext_vector_type(8))) short short8;
typedef __attribute__((ext_vector_type(4))) float f32x4;

__device__ __forceinline__ float bf2f(uint32_t u) {
    union { uint32_t i; float f; } v; v.i = u << 16; return v.f;
}
__device__ __forceinline__ uint32_t f2bf(float f) {
    union { float f; uint32_t i; } v; v.f = f;
    return (v.i + 0x7FFFu + ((v.i >> 16) & 1u)) >> 16;   // RNE
}

// ===========================================================================
// CSR build: bin (fixed-capacity buckets) -> bucket scan -> debin
// ===========================================================================
__global__ void __launch_bounds__(512) bin_pass(const int* __restrict__ src,
                                                const int* __restrict__ dst,
                                                int* __restrict__ gcnt,
                                                uint32_t* __restrict__ tmp)
{
    __shared__ int hist[NB];
    __shared__ int base[NB];
    int t = threadIdx.x;
    for (int i = t; i < NB; i += 512) hist[i] = 0;
    __syncthreads();
    const int e0 = blockIdx.x * EPB;
    int b_[8], s_[8], d_[8];
    #pragma unroll
    for (int k = 0; k < 8; ++k) {
        int e = e0 + k * 512 + t;
        if (e < N_EDGES) {
            int d = dst[e];
            b_[k] = d >> 7;
            d_[k] = d & 127;
            s_[k] = src[e];
            atomicAdd(&hist[b_[k]], 1);
        } else b_[k] = -1;
    }
    __syncthreads();
    for (int i = t; i < NB; i += 512) {
        int c = hist[i];
        base[i] = c ? atomicAdd(&gcnt[i], c) : 0;
        hist[i] = 0;
    }
    __syncthreads();
    #pragma unroll
    for (int k = 0; k < 8; ++k) {
        if (b_[k] >= 0) {
            int r = atomicAdd(&hist[b_[k]], 1);
            int pos = base[b_[k]] + r;
            if (pos < CAP)
                tmp[(size_t)b_[k] * CAP + pos] = ((uint32_t)s_[k] << 7) | (uint32_t)d_[k];
        }
    }
}

__global__ void __launch_bounds__(512) bucket_scan(const int* __restrict__ gcnt,
                                                   int* __restrict__ boff,
                                                   int* __restrict__ row_start)
{
    __shared__ int buf[512];
    int t = threadIdx.x;
    int v = (t < NB) ? gcnt[t] : 0;
    buf[t] = v;
    __syncthreads();
    #pragma unroll
    for (int off = 1; off < 512; off <<= 1) {
        int a = (t >= off) ? buf[t - off] : 0;
        __syncthreads();
        buf[t] += a;
        __syncthreads();
    }
    if (t < NB) boff[t] = buf[t] - v;
    if (t == 0) row_start[N_NODES] = N_EDGES;
}

__global__ void __launch_bounds__(256) debin2(const uint32_t* __restrict__ tmp,
                                              const int* __restrict__ gcnt,
                                              const int* __restrict__ boff,
                                              int* __restrict__ row_start,
                                              int* __restrict__ esrc)
{
    __shared__ int h[128];
    __shared__ int pre[128];
    __shared__ int cur[128];
    const int b = blockIdx.x;
    const int n0 = b * 128;
    const int nn = min(128, N_NODES - n0);
    const int t = threadIdx.x;
    const int cnt = min(gcnt[b], CAP);
    const int bb = boff[b];
    const uint32_t* te = tmp + (size_t)b * CAP;

    if (t < 128) h[t] = 0;
    __syncthreads();
    for (int p = t; p < cnt; p += 256)
        atomicAdd(&h[te[p] & 127u], 1);
    __syncthreads();
    if (t < 128) pre[t] = h[t];
    __syncthreads();
    #pragma unroll
    for (int off = 1; off < 128; off <<= 1) {
        int a = (t >= off && t < 128) ? pre[t - off] : 0;
        __syncthreads();
        if (t < 128) pre[t] += a;
        __syncthreads();
    }
    if (t < nn) {
        int rs = bb + pre[t] - h[t];   // exclusive
        row_start[n0 + t] = rs;
        cur[t] = rs;
    }
    __syncthreads();
    for (int p = t; p < cnt; p += 256) {
        uint32_t v = te[p];
        int pos = atomicAdd(&cur[v & 127u], 1);
        esrc[pos] = (int)(v >> 7);
    }
}

// ===========================================================================
// fused conversions: x -> bf16 (vectorized) + 6 weight transposes
// ===========================================================================
#define XB 3125   // N_NODES*IN_CH/8/256
__global__ void __launch_bounds__(256)
cvt_all(const float* __restrict__ x, u16* __restrict__ xb,
        const float* __restrict__ W1r, const float* __restrict__ W1n,
        const float* __restrict__ W2r, const float* __restrict__ W2n,
        const float* __restrict__ W3r, const float* __restrict__ W3n,
        u16* __restrict__ o1r, u16* __restrict__ o1n,
        u16* __restrict__ o2r, u16* __restrict__ o2n,
        u16* __restrict__ o3r, u16* __restrict__ o3n)
{
    if (blockIdx.x < XB) {
        int id = blockIdx.x * 256 + threadIdx.x;
        const float4 a = *reinterpret_cast<const float4*>(x + (size_t)id * 8);
        const float4 b = *reinterpret_cast<const float4*>(x + (size_t)id * 8 + 4);
        uint4 o;
        o.x = f2bf(a.x) | (f2bf(a.y) << 16);
        o.y = f2bf(a.z) | (f2bf(a.w) << 16);
        o.z = f2bf(b.x) | (f2bf(b.y) << 16);
        o.w = f2bf(b.z) | (f2bf(b.w) << 16);
        *reinterpret_cast<uint4*>(xb + (size_t)id * 8) = o;
        return;
    }
    int id = (blockIdx.x - XB) * 256 + threadIdx.x;   // 0..327679
    if (id < 65536) {                                  // W1: [128][256]
        int m = id >> 15;
        int r = id & 32767;
        int k = r >> 8, n = r & 255;
        const float* W = m ? W1n : W1r;
        u16* O = m ? o1n : o1r;
        O[n * 128 + k] = (u16)f2bf(W[r]);
    } else {                                           // W2/W3: [256][256]
        id -= 65536;
        int m = id >> 16;
        int r = id & 65535;
        int k = r >> 8, n = r & 255;
        const float* W = (m == 0) ? W2r : (m == 1) ? W2n : (m == 2) ? W3r : W3n;
        u16* O = (m == 0) ? o2r : (m == 1) ? o2n : (m == 2) ? o3r : o3n;
        O[n * 256 + k] = (u16)f2bf(W[r]);
    }
}

// ===========================================================================
// agg[i,:] = sum_{j in in(i)} feat[j,:]  — bf16, fp32 acc.
// Column-PHASED: each block loops NPH column slices (>=128 B each, so no
// L2-line over-fetch) with a barrier between -> instantaneous working set
// = 25.6/NPH MB, raising L2 hit rate. Co-resident blocks stay in phase
// because per-block edge work is near-uniform (~256 edges +/- 6%).
// ===========================================================================
template<int D, int NPH>
__global__ void __launch_bounds__(256)
gather_ph(const u16* __restrict__ feat, const int* __restrict__ row_start,
          const int* __restrict__ esrc, u16* __restrict__ agg)
{
    constexpr int CW = D / NPH;        // cols per phase (>= 64)
    constexpr int GS = CW / 8;         // threads per node per phase
    constexpr int NPB = 256 / GS;      // nodes per block
    const int node = blockIdx.x * NPB + threadIdx.x / GS;
    const int lane = threadIdx.x % GS;
    const bool act = node < N_NODES;
    int s = 0, e = 0;
    if (act) { s = row_start[node]; e = row_start[node + 1]; }

    #pragma unroll
    for (int p = 0; p < NPH; ++p) {
        const u16* fp = feat + p * CW + lane * 8;
        float acc[8] = {0.f, 0.f, 0.f, 0.f, 0.f, 0.f, 0.f, 0.f};
        auto add = [&](uint4 v) {
            acc[0] += bf2f(v.x & 0xFFFF); acc[1] += bf2f(v.x >> 16);
            acc[2] += bf2f(v.y & 0xFFFF); acc[3] += bf2f(v.y >> 16);
            acc[4] += bf2f(v.z & 0xFFFF); acc[5] += bf2f(v.z >> 16);
            acc[6] += bf2f(v.w & 0xFFFF); acc[7] += bf2f(v.w >> 16);
        };
        int j = s;
        for (; j + 3 < e; j += 4) {
            int s0 = esrc[j], s1 = esrc[j + 1], s2 = esrc[j + 2], s3 = esrc[j + 3];
            uint4 v0 = *reinterpret_cast<const uint4*>(fp + (size_t)s0 * D);
            uint4 v1 = *reinterpret_cast<const uint4*>(fp + (size_t)s1 * D);
            uint4 v2 = *reinterpret_cast<const uint4*>(fp + (size_t)s2 * D);
            uint4 v3 = *reinterpret_cast<const uint4*>(fp + (size_t)s3 * D);
            add(v0); add(v1); add(v2); add(v3);
        }
        for (; j < e; ++j) {
            uint4 v0 = *reinterpret_cast<const uint4*>(fp + (size_t)esrc[j] * D);
            add(v0);
        }
        if (act) {
            uint4 o;
            o.x = f2bf(acc[0]) | (f2bf(acc[1]) << 16);
            o.y = f2bf(acc[2]) | (f2bf(acc[3]) << 16);
            o.z = f2bf(acc[4]) | (f2bf(acc[5]) << 16);
            o.w = f2bf(acc[6]) | (f2bf(acc[7]) << 16);
            *reinterpret_cast<uint4*>(agg + (size_t)node * D + p * CW + lane * 8) = o;
        }
        if (p + 1 < NPH) __syncthreads();
    }
}

// ===========================================================================
// C[m,n] = act( A1@W1 + A2@W2 + bias )   — bf16 MFMA, fp32 acc, bf16 out
// ===========================================================================
template<int RELU>
__global__ void __launch_bounds__(256)
mfma_gemm(const u16* __restrict__ A1, const u16* __restrict__ A2,
          const u16* __restrict__ B1t, const u16* __restrict__ B2t,
          const float* __restrict__ bias,
          u16* __restrict__ C,
          int M, int K)
{
    __shared__ __align__(16) u16 As[128][40];
    __shared__ __align__(16) u16 Bs[128][40];

    const int orig = blockIdx.x;
    const int q = GEMM_WG / 8, r = GEMM_WG % 8;
    const int xcd = orig % 8;
    const int wg = (xcd < r ? xcd * (q + 1) : r * (q + 1) + (xcd - r) * q) + orig / 8;

    const int tid = threadIdx.x;
    const int bm = (wg >> 1) * 128;
    const int bn = (wg & 1) * 128;
    const int w  = tid >> 6;
    const int wm = (w >> 1) * 64;
    const int wn = (w & 1) * 64;
    const int l  = tid & 63;
    const int lr = l & 15;
    const int kb = (l >> 4) * 8;

    f32x4 acc[4][4];
    #pragma unroll
    for (int i = 0; i < 4; ++i)
        #pragma unroll
        for (int j = 0; j < 4; ++j)
            acc[i][j] = (f32x4){0.f, 0.f, 0.f, 0.f};

    const int row_s = tid >> 2;
    const int c8    = (tid & 3) * 8;

    for (int mat = 0; mat < 2; ++mat) {
        const u16* __restrict__ Ag = mat ? A2 : A1;
        const u16* __restrict__ Bg = mat ? B2t : B1t;
        for (int k0 = 0; k0 < K; k0 += 32) {
            #pragma unroll
            for (int it = 0; it < 2; ++it) {
                int row = row_s + it * 64;
                uint4 va = make_uint4(0u, 0u, 0u, 0u);
                int gr = bm + row;
                if (gr < M)
                    va = *reinterpret_cast<const uint4*>(Ag + (size_t)gr * K + k0 + c8);
                *reinterpret_cast<uint4*>(&As[row][c8]) = va;
                uint4 vb = *reinterpret_cast<const uint4*>(Bg + (size_t)(bn + row) * K + k0 + c8);
                *reinterpret_cast<uint4*>(&Bs[row][c8]) = vb;
            }
            __syncthreads();
            short8 af[4], bfr[4];
            #pragma unroll
            for (int f = 0; f < 4; ++f) {
                af[f]  = *reinterpret_cast<const short8*>(&As[wm + f * 16 + lr][kb]);
                bfr[f] = *reinterpret_cast<const short8*>(&Bs[wn + f * 16 + lr][kb]);
            }
            #pragma unroll
            for (int fm = 0; fm < 4; ++fm)
                #pragma unroll
                for (int fn = 0; fn < 4; ++fn)
                    acc[fm][fn] = __builtin_amdgcn_mfma_f32_16x16x32_bf16(
                        af[fm], bfr[fn], acc[fm][fn], 0, 0, 0);
            __syncthreads();
        }
    }

    const int r4 = (l >> 4) * 4;
    #pragma unroll
    for (int fm = 0; fm < 4; ++fm) {
        #pragma unroll
        for (int rr = 0; rr < 4; ++rr) {
            int row = bm + wm + fm * 16 + r4 + rr;
            if (row >= M) continue;
            #pragma unroll
            for (int fn = 0; fn < 4; ++fn) {
                int col = bn + wn + fn * 16 + lr;
                float v = acc[fm][fn][rr] + bias[col];
                if (RELU) v = fmaxf(v, 0.f);
                C[(size_t)row * HID + col] = (u16)f2bf(v);
            }
        }
    }
}

// ===========================================================================
// Pooling (batch sorted): inline binary search, two-stage mean + classifier
// ===========================================================================
__device__ __forceinline__ int lower_bound_g(const int* __restrict__ batch, int g)
{
    int lo = 0, hi = N_NODES;
    while (lo < hi) {
        int mid = (lo + hi) >> 1;
        if (batch[mid] < g) lo = mid + 1; else hi = mid;
    }
    return lo;
}

__global__ void pool1_kernel(const u16* __restrict__ h, const int* __restrict__ batch,
                             float* __restrict__ partial)
{
    int g = blockIdx.x >> 3;
    int c = blockIdx.x & 7;
    int t = threadIdx.x;      // 256
    int s = lower_bound_g(batch, g);
    int e = lower_bound_g(batch, g + 1);
    int cnt = e - s;
    int a = s + (int)(((long long)cnt * c) >> 3);
    int b = s + (int)(((long long)cnt * (c + 1)) >> 3);
    float acc = 0.f;
    for (int i = a; i < b; ++i)
        acc += bf2f(h[(size_t)i * HID + t]);
    partial[(size_t)blockIdx.x * HID + t] = acc;
}

__global__ void pool2_final(const float* __restrict__ partial, const int* __restrict__ batch,
                            const float* __restrict__ W_lin, const float* __restrict__ b_lin,
                            float* __restrict__ out)
{
    __shared__ float v[HID];
    int g = blockIdx.x;
    int t = threadIdx.x;
    float acc = 0.f;
    #pragma unroll
    for (int c = 0; c < 8; ++c)
        acc += partial[(size_t)(g * 8 + c) * HID + t];
    float cnt = fmaxf((float)(lower_bound_g(batch, g + 1) - lower_bound_g(batch, g)), 1.f);
    v[t] = acc / cnt;
    __syncthreads();
    if (t < N_CLASSES) {
        float s = b_lin[t];
        for (int k = 0; k < HID; ++k)
            s += v[k] * W_lin[k * N_CLASSES + t];
        out[g * N_CLASSES + t] = s;
    }
}

// ===========================================================================
extern "C" void kernel_launch(void* const* d_in, const int* in_sizes, int n_in,
                              void* d_out, int out_size, void* d_ws, size_t ws_size,
                              hipStream_t stream)
{
    const float* x     = (const float*)d_in[0];
    const int*   ei    = (const int*)d_in[1];
    const int*   batch = (const int*)d_in[2];
    const float* W1r = (const float*)d_in[3];
    const float* W1n = (const float*)d_in[4];
    const float* b1  = (const float*)d_in[5];
    const float* W2r = (const float*)d_in[6];
    const float* W2n = (const float*)d_in[7];
    const float* b2  = (const float*)d_in[8];
    const float* W3r = (const float*)d_in[9];
    const float* W3n = (const float*)d_in[10];
    const float* b3  = (const float*)d_in[11];
    const float* Wl  = (const float*)d_in[12];
    const float* bl  = (const float*)d_in[13];
    float* out = (float*)d_out;

    const int* src = ei;
    const int* dst = ei + N_EDGES;

    char* base = (char*)d_ws;
    size_t off = 0;
    auto alloc = [&](size_t bytes) { char* p = base + off; off += (bytes + 255) & ~(size_t)255; return p; };
    u16* x_bf = (u16*)alloc((size_t)N_NODES * IN_CH * 2);
    u16* hA   = (u16*)alloc((size_t)N_NODES * HID * 2);
    u16* hB   = (u16*)alloc((size_t)N_NODES * HID * 2);
    u16* agg  = (u16*)alloc((size_t)N_NODES * HID * 2);
    u16* wt1r = (u16*)alloc((size_t)HID * IN_CH * 2);
    u16* wt1n = (u16*)alloc((size_t)HID * IN_CH * 2);
    u16* wt2r = (u16*)alloc((size_t)HID * HID * 2);
    u16* wt2n = (u16*)alloc((size_t)HID * HID * 2);
    u16* wt3r = (u16*)alloc((size_t)HID * HID * 2);
    u16* wt3n = (u16*)alloc((size_t)HID * HID * 2);
    float* partial = (float*)alloc((size_t)N_GRAPHS * 8 * HID * 4);
    int* row_start = (int*)alloc((size_t)(N_NODES + 1) * 4);
    int* esrc      = (int*)alloc((size_t)N_EDGES * 4);
    uint32_t* tmp  = (uint32_t*)alloc((size_t)NB * CAP * 4);
    int* gcnt      = (int*)alloc((size_t)NB * 4);
    int* boff      = (int*)alloc((size_t)NB * 4);

    // ---- CSR build (4 dispatches: memset + bin + scan + debin) ----
    hipMemsetAsync(gcnt, 0, NB * sizeof(int), stream);
    bin_pass<<<(N_EDGES + EPB - 1) / EPB, 512, 0, stream>>>(src, dst, gcnt, tmp);
    bucket_scan<<<1, 512, 0, stream>>>(gcnt, boff, row_start);
    debin2<<<NB, 256, 0, stream>>>(tmp, gcnt, boff, row_start, esrc);

    // ---- conversions (1 dispatch) ----
    cvt_all<<<XB + 1280, 256, 0, stream>>>(x, x_bf, W1r, W1n, W2r, W2n, W3r, W3n,
                                           wt1r, wt1n, wt2r, wt2n, wt3r, wt3n);

    // gather grids: D=128 -> 32 nodes/block; D=256 -> 16 nodes/block
    const int G128 = (N_NODES + 31) / 32;
    const int G256 = (N_NODES + 15) / 16;

    // ---- layer 1 (K=128, relu) ----
    gather_ph<IN_CH, 2><<<G128, 256, 0, stream>>>(x_bf, row_start, esrc, agg);
    mfma_gemm<1><<<GEMM_WG, 256, 0, stream>>>(x_bf, agg, wt1r, wt1n, b1, hA, N_NODES, IN_CH);

    // ---- layer 2 (K=256, relu) ----
    gather_ph<HID, 2><<<G256, 256, 0, stream>>>(hA, row_start, esrc, agg);
    mfma_gemm<1><<<GEMM_WG, 256, 0, stream>>>(hA, agg, wt2r, wt2n, b2, hB, N_NODES, HID);

    // ---- layer 3 (K=256, no relu) ----
    gather_ph<HID, 2><<<G256, 256, 0, stream>>>(hB, row_start, esrc, agg);
    mfma_gemm<0><<<GEMM_WG, 256, 0, stream>>>(hB, agg, wt3r, wt3n, b3, hA, N_NODES, HID);

    // ---- pool + classifier (2 dispatches) ----
    pool1_kernel<<<N_GRAPHS * 8, HID, 0, stream>>>(hA, batch, partial);
    pool2_final<<<N_GRAPHS, HID, 0, stream>>>(partial, batch, Wl, bl, out);
}

// Round 11
// 302.690 us; speedup vs baseline: 1.6734x; 1.0800x over previous
//
#include <hip/hip_runtime.h>
#include <stdint.h>

#define N_NODES 50000
#define N_EDGES 800000
#define IN_CH 128
#define HID 256
#define N_GRAPHS 64
#define N_CLASSES 10

#define GEMM_WG ((N_NODES + 127) / 128)       // 391 blocks (full-width tiles)
#define NB ((N_NODES + 127) / 128)            // 391 dst buckets (128 nodes each)
#define EPB 4096                              // edges per bin_pass block
#define CAP 4096                              // slots per bucket (mean 2048, 45 sigma)

typedef unsigned short u16;
typedef __attribute__((ext_vector_type(8))) short short8;
typedef __attribute__((ext_vector_type(4))) float f32x4;

__device__ __forceinline__ float bf2f(uint32_t u) {
    union { uint32_t i; float f; } v; v.i = u << 16; return v.f;
}
__device__ __forceinline__ uint32_t f2bf(float f) {
    union { float f; uint32_t i; } v; v.f = f;
    return (v.i + 0x7FFFu + ((v.i >> 16) & 1u)) >> 16;   // RNE
}

// ===========================================================================
// CSR build: bin (fixed-capacity buckets) -> bucket scan -> debin
// ===========================================================================
__global__ void __launch_bounds__(512) bin_pass(const int* __restrict__ src,
                                                const int* __restrict__ dst,
                                                int* __restrict__ gcnt,
                                                uint32_t* __restrict__ tmp)
{
    __shared__ int hist[NB];
    __shared__ int base[NB];
    int t = threadIdx.x;
    for (int i = t; i < NB; i += 512) hist[i] = 0;
    __syncthreads();
    const int e0 = blockIdx.x * EPB;
    int b_[8], s_[8], d_[8];
    #pragma unroll
    for (int k = 0; k < 8; ++k) {
        int e = e0 + k * 512 + t;
        if (e < N_EDGES) {
            int d = dst[e];
            b_[k] = d >> 7;
            d_[k] = d & 127;
            s_[k] = src[e];
            atomicAdd(&hist[b_[k]], 1);
        } else b_[k] = -1;
    }
    __syncthreads();
    for (int i = t; i < NB; i += 512) {
        int c = hist[i];
        base[i] = c ? atomicAdd(&gcnt[i], c) : 0;
        hist[i] = 0;
    }
    __syncthreads();
    #pragma unroll
    for (int k = 0; k < 8; ++k) {
        if (b_[k] >= 0) {
            int r = atomicAdd(&hist[b_[k]], 1);
            int pos = base[b_[k]] + r;
            if (pos < CAP)
                tmp[(size_t)b_[k] * CAP + pos] = ((uint32_t)s_[k] << 7) | (uint32_t)d_[k];
        }
    }
}

__global__ void __launch_bounds__(512) bucket_scan(const int* __restrict__ gcnt,
                                                   int* __restrict__ boff,
                                                   int* __restrict__ row_start)
{
    __shared__ int buf[512];
    int t = threadIdx.x;
    int v = (t < NB) ? gcnt[t] : 0;
    buf[t] = v;
    __syncthreads();
    #pragma unroll
    for (int off = 1; off < 512; off <<= 1) {
        int a = (t >= off) ? buf[t - off] : 0;
        __syncthreads();
        buf[t] += a;
        __syncthreads();
    }
    if (t < NB) boff[t] = buf[t] - v;
    if (t == 0) row_start[N_NODES] = N_EDGES;
}

__global__ void __launch_bounds__(256) debin2(const uint32_t* __restrict__ tmp,
                                              const int* __restrict__ gcnt,
                                              const int* __restrict__ boff,
                                              int* __restrict__ row_start,
                                              int* __restrict__ esrc)
{
    __shared__ int h[128];
    __shared__ int pre[128];
    __shared__ int cur[128];
    const int b = blockIdx.x;
    const int n0 = b * 128;
    const int nn = min(128, N_NODES - n0);
    const int t = threadIdx.x;
    const int cnt = min(gcnt[b], CAP);
    const int bb = boff[b];
    const uint32_t* te = tmp + (size_t)b * CAP;

    if (t < 128) h[t] = 0;
    __syncthreads();
    for (int p = t; p < cnt; p += 256)
        atomicAdd(&h[te[p] & 127u], 1);
    __syncthreads();
    if (t < 128) pre[t] = h[t];
    __syncthreads();
    #pragma unroll
    for (int off = 1; off < 128; off <<= 1) {
        int a = (t >= off && t < 128) ? pre[t - off] : 0;
        __syncthreads();
        if (t < 128) pre[t] += a;
        __syncthreads();
    }
    if (t < nn) {
        int rs = bb + pre[t] - h[t];   // exclusive
        row_start[n0 + t] = rs;
        cur[t] = rs;
    }
    __syncthreads();
    for (int p = t; p < cnt; p += 256) {
        uint32_t v = te[p];
        int pos = atomicAdd(&cur[v & 127u], 1);
        esrc[pos] = (int)(v >> 7);
    }
}

// ===========================================================================
// fused conversions: x -> bf16 (vectorized) + 6 weight transposes
// ===========================================================================
#define XB 3125   // N_NODES*IN_CH/8/256
__global__ void __launch_bounds__(256)
cvt_all(const float* __restrict__ x, u16* __restrict__ xb,
        const float* __restrict__ W1r, const float* __restrict__ W1n,
        const float* __restrict__ W2r, const float* __restrict__ W2n,
        const float* __restrict__ W3r, const float* __restrict__ W3n,
        u16* __restrict__ o1r, u16* __restrict__ o1n,
        u16* __restrict__ o2r, u16* __restrict__ o2n,
        u16* __restrict__ o3r, u16* __restrict__ o3n)
{
    if (blockIdx.x < XB) {
        int id = blockIdx.x * 256 + threadIdx.x;
        const float4 a = *reinterpret_cast<const float4*>(x + (size_t)id * 8);
        const float4 b = *reinterpret_cast<const float4*>(x + (size_t)id * 8 + 4);
        uint4 o;
        o.x = f2bf(a.x) | (f2bf(a.y) << 16);
        o.y = f2bf(a.z) | (f2bf(a.w) << 16);
        o.z = f2bf(b.x) | (f2bf(b.y) << 16);
        o.w = f2bf(b.z) | (f2bf(b.w) << 16);
        *reinterpret_cast<uint4*>(xb + (size_t)id * 8) = o;
        return;
    }
    int id = (blockIdx.x - XB) * 256 + threadIdx.x;   // 0..327679
    if (id < 65536) {                                  // W1: [128][256]
        int m = id >> 15;
        int r = id & 32767;
        int k = r >> 8, n = r & 255;
        const float* W = m ? W1n : W1r;
        u16* O = m ? o1n : o1r;
        O[n * 128 + k] = (u16)f2bf(W[r]);
    } else {                                           // W2/W3: [256][256]
        id -= 65536;
        int m = id >> 16;
        int r = id & 65535;
        int k = r >> 8, n = r & 255;
        const float* W = (m == 0) ? W2r : (m == 1) ? W2n : (m == 2) ? W3r : W3n;
        u16* O = (m == 0) ? o2r : (m == 1) ? o2n : (m == 2) ? o3r : o3n;
        O[n * 256 + k] = (u16)f2bf(W[r]);
    }
}

// ===========================================================================
// agg[i,:] = sum_{j in in(i)} feat[j,:]  — bf16, fp32 acc, column-phased
// ===========================================================================
template<int D, int NPH>
__global__ void __launch_bounds__(256)
gather_ph(const u16* __restrict__ feat, const int* __restrict__ row_start,
          const int* __restrict__ esrc, u16* __restrict__ agg)
{
    constexpr int CW = D / NPH;        // cols per phase (>= 64)
    constexpr int GS = CW / 8;         // threads per node per phase
    constexpr int NPB = 256 / GS;      // nodes per block
    const int node = blockIdx.x * NPB + threadIdx.x / GS;
    const int lane = threadIdx.x % GS;
    const bool act = node < N_NODES;
    int s = 0, e = 0;
    if (act) { s = row_start[node]; e = row_start[node + 1]; }

    #pragma unroll
    for (int p = 0; p < NPH; ++p) {
        const u16* fp = feat + p * CW + lane * 8;
        float acc[8] = {0.f, 0.f, 0.f, 0.f, 0.f, 0.f, 0.f, 0.f};
        auto add = [&](uint4 v) {
            acc[0] += bf2f(v.x & 0xFFFF); acc[1] += bf2f(v.x >> 16);
            acc[2] += bf2f(v.y & 0xFFFF); acc[3] += bf2f(v.y >> 16);
            acc[4] += bf2f(v.z & 0xFFFF); acc[5] += bf2f(v.z >> 16);
            acc[6] += bf2f(v.w & 0xFFFF); acc[7] += bf2f(v.w >> 16);
        };
        int j = s;
        for (; j + 3 < e; j += 4) {
            int s0 = esrc[j], s1 = esrc[j + 1], s2 = esrc[j + 2], s3 = esrc[j + 3];
            uint4 v0 = *reinterpret_cast<const uint4*>(fp + (size_t)s0 * D);
            uint4 v1 = *reinterpret_cast<const uint4*>(fp + (size_t)s1 * D);
            uint4 v2 = *reinterpret_cast<const uint4*>(fp + (size_t)s2 * D);
            uint4 v3 = *reinterpret_cast<const uint4*>(fp + (size_t)s3 * D);
            add(v0); add(v1); add(v2); add(v3);
        }
        for (; j < e; ++j) {
            uint4 v0 = *reinterpret_cast<const uint4*>(fp + (size_t)esrc[j] * D);
            add(v0);
        }
        if (act) {
            uint4 o;
            o.x = f2bf(acc[0]) | (f2bf(acc[1]) << 16);
            o.y = f2bf(acc[2]) | (f2bf(acc[3]) << 16);
            o.z = f2bf(acc[4]) | (f2bf(acc[5]) << 16);
            o.w = f2bf(acc[6]) | (f2bf(acc[7]) << 16);
            *reinterpret_cast<uint4*>(agg + (size_t)node * D + p * CW + lane * 8) = o;
        }
        if (p + 1 < NPH) __syncthreads();
    }
}

// ===========================================================================
// C[m,n] = act( A1@W1 + A2@W2 + bias )   — bf16 MFMA, fp32 acc, bf16 out
// FULL-WIDTH tile: BM=128 x BN=256 per 512-thread block (8 waves, 64x64 each)
// -> each A row-panel is read exactly ONCE (was twice with 2 col-tiles).
// ===========================================================================
template<int RELU>
__global__ void __launch_bounds__(512)
mfma_gemm(const u16* __restrict__ A1, const u16* __restrict__ A2,
          const u16* __restrict__ B1t, const u16* __restrict__ B2t,
          const float* __restrict__ bias,
          u16* __restrict__ C,
          int M, int K)
{
    __shared__ __align__(16) u16 As[128][40];
    __shared__ __align__(16) u16 Bs[256][40];

    // bijective XCD chunking (m204)
    const int orig = blockIdx.x;
    const int q = GEMM_WG / 8, r = GEMM_WG % 8;
    const int xcd = orig % 8;
    const int wg = (xcd < r ? xcd * (q + 1) : r * (q + 1) + (xcd - r) * q) + orig / 8;

    const int tid = threadIdx.x;
    const int bm = wg * 128;
    const int w  = tid >> 6;          // 0..7
    const int wm = (w >> 2) * 64;     // 0 or 64
    const int wn = (w & 3) * 64;      // 0,64,128,192
    const int l  = tid & 63;
    const int lr = l & 15;
    const int kb = (l >> 4) * 8;

    f32x4 acc[4][4];
    #pragma unroll
    for (int i = 0; i < 4; ++i)
        #pragma unroll
        for (int j = 0; j < 4; ++j)
            acc[i][j] = (f32x4){0.f, 0.f, 0.f, 0.f};

    const int row_s = tid >> 2;       // 0..127
    const int c8    = (tid & 3) * 8;

    for (int mat = 0; mat < 2; ++mat) {
        const u16* __restrict__ Ag = mat ? A2 : A1;
        const u16* __restrict__ Bg = mat ? B2t : B1t;
        for (int k0 = 0; k0 < K; k0 += 32) {
            // A tile: 128 rows x 32 k -> 512 uint4, 1 per thread
            {
                uint4 va = make_uint4(0u, 0u, 0u, 0u);
                int gr = bm + row_s;
                if (gr < M)
                    va = *reinterpret_cast<const uint4*>(Ag + (size_t)gr * K + k0 + c8);
                *reinterpret_cast<uint4*>(&As[row_s][c8]) = va;
            }
            // B tile: 256 rows x 32 k -> 1024 uint4, 2 per thread
            #pragma unroll
            for (int it = 0; it < 2; ++it) {
                int row = row_s + it * 128;
                uint4 vb = *reinterpret_cast<const uint4*>(Bg + (size_t)row * K + k0 + c8);
                *reinterpret_cast<uint4*>(&Bs[row][c8]) = vb;
            }
            __syncthreads();
            short8 af[4], bfr[4];
            #pragma unroll
            for (int f = 0; f < 4; ++f) {
                af[f]  = *reinterpret_cast<const short8*>(&As[wm + f * 16 + lr][kb]);
                bfr[f] = *reinterpret_cast<const short8*>(&Bs[wn + f * 16 + lr][kb]);
            }
            #pragma unroll
            for (int fm = 0; fm < 4; ++fm)
                #pragma unroll
                for (int fn = 0; fn < 4; ++fn)
                    acc[fm][fn] = __builtin_amdgcn_mfma_f32_16x16x32_bf16(
                        af[fm], bfr[fn], acc[fm][fn], 0, 0, 0);
            __syncthreads();
        }
    }

    const int r4 = (l >> 4) * 4;
    #pragma unroll
    for (int fm = 0; fm < 4; ++fm) {
        #pragma unroll
        for (int rr = 0; rr < 4; ++rr) {
            int row = bm + wm + fm * 16 + r4 + rr;
            if (row >= M) continue;
            #pragma unroll
            for (int fn = 0; fn < 4; ++fn) {
                int col = wn + fn * 16 + lr;
                float v = acc[fm][fn][rr] + bias[col];
                if (RELU) v = fmaxf(v, 0.f);
                C[(size_t)row * HID + col] = (u16)f2bf(v);
            }
        }
    }
}

// ===========================================================================
// Pooling (batch sorted): inline binary search, two-stage mean + classifier
// ===========================================================================
__device__ __forceinline__ int lower_bound_g(const int* __restrict__ batch, int g)
{
    int lo = 0, hi = N_NODES;
    while (lo < hi) {
        int mid = (lo + hi) >> 1;
        if (batch[mid] < g) lo = mid + 1; else hi = mid;
    }
    return lo;
}

__global__ void pool1_kernel(const u16* __restrict__ h, const int* __restrict__ batch,
                             float* __restrict__ partial)
{
    int g = blockIdx.x >> 3;
    int c = blockIdx.x & 7;
    int t = threadIdx.x;      // 256
    int s = lower_bound_g(batch, g);
    int e = lower_bound_g(batch, g + 1);
    int cnt = e - s;
    int a = s + (int)(((long long)cnt * c) >> 3);
    int b = s + (int)(((long long)cnt * (c + 1)) >> 3);
    float acc = 0.f;
    for (int i = a; i < b; ++i)
        acc += bf2f(h[(size_t)i * HID + t]);
    partial[(size_t)blockIdx.x * HID + t] = acc;
}

__global__ void pool2_final(const float* __restrict__ partial, const int* __restrict__ batch,
                            const float* __restrict__ W_lin, const float* __restrict__ b_lin,
                            float* __restrict__ out)
{
    __shared__ float v[HID];
    int g = blockIdx.x;
    int t = threadIdx.x;
    float acc = 0.f;
    #pragma unroll
    for (int c = 0; c < 8; ++c)
        acc += partial[(size_t)(g * 8 + c) * HID + t];
    float cnt = fmaxf((float)(lower_bound_g(batch, g + 1) - lower_bound_g(batch, g)), 1.f);
    v[t] = acc / cnt;
    __syncthreads();
    if (t < N_CLASSES) {
        float s = b_lin[t];
        for (int k = 0; k < HID; ++k)
            s += v[k] * W_lin[k * N_CLASSES + t];
        out[g * N_CLASSES + t] = s;
    }
}

// ===========================================================================
extern "C" void kernel_launch(void* const* d_in, const int* in_sizes, int n_in,
                              void* d_out, int out_size, void* d_ws, size_t ws_size,
                              hipStream_t stream)
{
    const float* x     = (const float*)d_in[0];
    const int*   ei    = (const int*)d_in[1];
    const int*   batch = (const int*)d_in[2];
    const float* W1r = (const float*)d_in[3];
    const float* W1n = (const float*)d_in[4];
    const float* b1  = (const float*)d_in[5];
    const float* W2r = (const float*)d_in[6];
    const float* W2n = (const float*)d_in[7];
    const float* b2  = (const float*)d_in[8];
    const float* W3r = (const float*)d_in[9];
    const float* W3n = (const float*)d_in[10];
    const float* b3  = (const float*)d_in[11];
    const float* Wl  = (const float*)d_in[12];
    const float* bl  = (const float*)d_in[13];
    float* out = (float*)d_out;

    const int* src = ei;
    const int* dst = ei + N_EDGES;

    char* base = (char*)d_ws;
    size_t off = 0;
    auto alloc = [&](size_t bytes) { char* p = base + off; off += (bytes + 255) & ~(size_t)255; return p; };
    u16* x_bf = (u16*)alloc((size_t)N_NODES * IN_CH * 2);
    u16* hA   = (u16*)alloc((size_t)N_NODES * HID * 2);
    u16* hB   = (u16*)alloc((size_t)N_NODES * HID * 2);
    u16* agg  = (u16*)alloc((size_t)N_NODES * HID * 2);
    u16* wt1r = (u16*)alloc((size_t)HID * IN_CH * 2);
    u16* wt1n = (u16*)alloc((size_t)HID * IN_CH * 2);
    u16* wt2r = (u16*)alloc((size_t)HID * HID * 2);
    u16* wt2n = (u16*)alloc((size_t)HID * HID * 2);
    u16* wt3r = (u16*)alloc((size_t)HID * HID * 2);
    u16* wt3n = (u16*)alloc((size_t)HID * HID * 2);
    float* partial = (float*)alloc((size_t)N_GRAPHS * 8 * HID * 4);
    int* row_start = (int*)alloc((size_t)(N_NODES + 1) * 4);
    int* esrc      = (int*)alloc((size_t)N_EDGES * 4);
    uint32_t* tmp  = (uint32_t*)alloc((size_t)NB * CAP * 4);
    int* gcnt      = (int*)alloc((size_t)NB * 4);
    int* boff      = (int*)alloc((size_t)NB * 4);

    // ---- CSR build (4 dispatches: memset + bin + scan + debin) ----
    hipMemsetAsync(gcnt, 0, NB * sizeof(int), stream);
    bin_pass<<<(N_EDGES + EPB - 1) / EPB, 512, 0, stream>>>(src, dst, gcnt, tmp);
    bucket_scan<<<1, 512, 0, stream>>>(gcnt, boff, row_start);
    debin2<<<NB, 256, 0, stream>>>(tmp, gcnt, boff, row_start, esrc);

    // ---- conversions (1 dispatch) ----
    cvt_all<<<XB + 1280, 256, 0, stream>>>(x, x_bf, W1r, W1n, W2r, W2n, W3r, W3n,
                                           wt1r, wt1n, wt2r, wt2n, wt3r, wt3n);

    // gather grids: D=128 -> 32 nodes/block; D=256 -> 16 nodes/block
    const int G128 = (N_NODES + 31) / 32;
    const int G256 = (N_NODES + 15) / 16;

    // ---- layer 1 (K=128, relu) ----
    gather_ph<IN_CH, 2><<<G128, 256, 0, stream>>>(x_bf, row_start, esrc, agg);
    mfma_gemm<1><<<GEMM_WG, 512, 0, stream>>>(x_bf, agg, wt1r, wt1n, b1, hA, N_NODES, IN_CH);

    // ---- layer 2 (K=256, relu) ----
    gather_ph<HID, 2><<<G256, 256, 0, stream>>>(hA, row_start, esrc, agg);
    mfma_gemm<1><<<GEMM_WG, 512, 0, stream>>>(hA, agg, wt2r, wt2n, b2, hB, N_NODES, HID);

    // ---- layer 3 (K=256, no relu) ----
    gather_ph<HID, 2><<<G256, 256, 0, stream>>>(hB, row_start, esrc, agg);
    mfma_gemm<0><<<GEMM_WG, 512, 0, stream>>>(hB, agg, wt3r, wt3n, b3, hA, N_NODES, HID);

    // ---- pool + classifier (2 dispatches) ----
    pool1_kernel<<<N_GRAPHS * 8, HID, 0, stream>>>(hA, batch, partial);
    pool2_final<<<N_GRAPHS, HID, 0, stream>>>(partial, batch, Wl, bl, out);
}